// Round 13
// baseline (1520.929 us; speedup 1.0000x reference)
//
#include <hip/hip_runtime.h>

#define NB   512
#define NV   20480
#define NA   51200
#define EVV  163840
#define EAA  409600
#define EVA  61440
#define DV   1024
#define DA   128
#define HD   512
#define NOUT 128
#define NL   4

#define VTILES 160           // NV/128
#define ATILES 400           // NA/128
#define GSEC0  (VTILES * 4)  // 640  (hs)
#define GSEC1  (GSEC0 * 2)   // 1280 (hv)
#define GTOT   (GSEC1 + ATILES * 4)  // 2880
#define ABLK   (NA / 4)      // 12800 audio gather blocks
#define GBLK   ((NA + NV) / 4)

typedef __attribute__((ext_vector_type(8))) short short8;
typedef __attribute__((ext_vector_type(8))) unsigned short ushort8;
typedef __attribute__((ext_vector_type(4))) float f32x4;

__device__ inline unsigned short f2bf(float f) {
  unsigned u = __float_as_uint(f);
  return (unsigned short)((u + 0x7fffu + ((u >> 16) & 1u)) >> 16);
}
__device__ inline float bf2f(unsigned short h) {
  return __uint_as_float((unsigned)h << 16);
}

// ---- merged MFMA GEMM; norm affine hoisted out of the K-loop ---------------
// sections: [0,640) hs=xv@Ws', [640,1280) hv=xv@Wv', [1280,2880) ha=xa@Wa'.
// AFF=1 (layers >=1): A-staging = relu+cast only (lnw folded into W');
// epilogue applies h = rstd*acc - rstd*mean*s[col] + t[col]  (st = [s|t]).
template <int AFF>
__global__ __launch_bounds__(256) void mfma_gemm3(const float* __restrict__ xv,
    const float* __restrict__ xa,
    const unsigned short* __restrict__ Wt_s, const unsigned short* __restrict__ Wt_v,
    const unsigned short* __restrict__ Wt_a,
    unsigned short* __restrict__ S_s, unsigned short* __restrict__ S_v,
    unsigned short* __restrict__ S_a, int Kv, int Ka,
    const float* __restrict__ mean_v, const float* __restrict__ rstd_v,
    const float* __restrict__ mean_a, const float* __restrict__ rstd_a,
    const float* __restrict__ st_s, const float* __restrict__ st_v,
    const float* __restrict__ st_a) {
  __shared__ unsigned short As[128 * 40];
  __shared__ unsigned short Bs[128 * 40];
  const int id = blockIdx.x;
  const float* A; const unsigned short* Bt; unsigned short* C; int K; int lid;
  const float* stp; bool video;
  if (id < GSEC0)      { A = xv; Bt = Wt_s; C = S_s; K = Kv; lid = id; stp = st_s; video = true; }
  else if (id < GSEC1) { A = xv; Bt = Wt_v; C = S_v; K = Kv; lid = id - GSEC0; stp = st_v; video = true; }
  else                 { A = xa; Bt = Wt_a; C = S_a; K = Ka; lid = id - GSEC1; stp = st_a; video = false; }
  const int xcd = lid & 7;
  const int j = lid >> 3;
  const int bn = j & 3;
  const int bm = xcd + ((j >> 2) << 3);
  const int tid = threadIdx.x;
  const int l = tid & 63, wid = tid >> 6;
  const int wr = wid >> 1, wc = wid & 1;
  const int r = tid >> 1;
  const int kh = (tid & 1) << 4;

  const float* ap = A + (size_t)(bm * 128 + r) * K + kh;
  const unsigned short* btp = Bt + (size_t)(bn * 128 + r) * K + kh;

  f32x4 acc[4][4] = {};
  const int fr = l & 15, fq = l >> 4;
  const int arow = (wr * 64 + fr) * 40 + fq * 8;
  const int brow = (wc * 64 + fr) * 40 + fq * 8;

  for (int k0 = 0; k0 < K; k0 += 32) {
    float4 f0 = *(const float4*)(ap + k0 + 0);
    float4 f1 = *(const float4*)(ap + k0 + 4);
    float4 f2 = *(const float4*)(ap + k0 + 8);
    float4 f3 = *(const float4*)(ap + k0 + 12);
    short8 bv0 = *(const short8*)(btp + k0);
    short8 bv1 = *(const short8*)(btp + k0 + 8);
    if (AFF) {   // layers >=1: A operand is relu(raw); lnw lives in W'
      f0.x = fmaxf(f0.x, 0.f); f0.y = fmaxf(f0.y, 0.f);
      f0.z = fmaxf(f0.z, 0.f); f0.w = fmaxf(f0.w, 0.f);
      f1.x = fmaxf(f1.x, 0.f); f1.y = fmaxf(f1.y, 0.f);
      f1.z = fmaxf(f1.z, 0.f); f1.w = fmaxf(f1.w, 0.f);
      f2.x = fmaxf(f2.x, 0.f); f2.y = fmaxf(f2.y, 0.f);
      f2.z = fmaxf(f2.z, 0.f); f2.w = fmaxf(f2.w, 0.f);
      f3.x = fmaxf(f3.x, 0.f); f3.y = fmaxf(f3.y, 0.f);
      f3.z = fmaxf(f3.z, 0.f); f3.w = fmaxf(f3.w, 0.f);
    }
    short8 p0, p1;
    p0[0] = (short)f2bf(f0.x); p0[1] = (short)f2bf(f0.y);
    p0[2] = (short)f2bf(f0.z); p0[3] = (short)f2bf(f0.w);
    p0[4] = (short)f2bf(f1.x); p0[5] = (short)f2bf(f1.y);
    p0[6] = (short)f2bf(f1.z); p0[7] = (short)f2bf(f1.w);
    p1[0] = (short)f2bf(f2.x); p1[1] = (short)f2bf(f2.y);
    p1[2] = (short)f2bf(f2.z); p1[3] = (short)f2bf(f2.w);
    p1[4] = (short)f2bf(f3.x); p1[5] = (short)f2bf(f3.y);
    p1[6] = (short)f2bf(f3.z); p1[7] = (short)f2bf(f3.w);
    __syncthreads();
    *(short8*)&As[r * 40 + kh] = p0;
    *(short8*)&As[r * 40 + kh + 8] = p1;
    *(short8*)&Bs[r * 40 + kh] = bv0;
    *(short8*)&Bs[r * 40 + kh + 8] = bv1;
    __syncthreads();
    short8 a[4], b[4];
#pragma unroll
    for (int m = 0; m < 4; ++m) a[m] = *(const short8*)&As[arow + m * 16 * 40];
#pragma unroll
    for (int n = 0; n < 4; ++n) b[n] = *(const short8*)&Bs[brow + n * 16 * 40];
#pragma unroll
    for (int m = 0; m < 4; ++m)
#pragma unroll
      for (int n = 0; n < 4; ++n)
        acc[m][n] = __builtin_amdgcn_mfma_f32_16x16x32_bf16(a[m], b[n], acc[m][n], 0, 0, 0);
  }

  // epilogue: per-row scalars (rstd, rstd*mean) + per-col (s, t)
#pragma unroll
  for (int m = 0; m < 4; ++m) {
    float rs4[4], rm4[4];
    if (AFF) {
#pragma unroll
      for (int j2 = 0; j2 < 4; ++j2) {
        int row = bm * 128 + wr * 64 + m * 16 + fq * 4 + j2;
        int g = video ? row / 40 : row / 100;
        float rs_ = video ? rstd_v[g] : rstd_a[g];
        float mn_ = video ? mean_v[g] : mean_a[g];
        rs4[j2] = rs_;
        rm4[j2] = rs_ * mn_;
      }
    }
#pragma unroll
    for (int n = 0; n < 4; ++n) {
      int col = bn * 128 + wc * 64 + n * 16 + fr;
      float s_c = 0.f, t_c = 0.f;
      if (AFF) { s_c = stp[col]; t_c = stp[512 + col]; }
#pragma unroll
      for (int j2 = 0; j2 < 4; ++j2) {
        int row = bm * 128 + wr * 64 + m * 16 + fq * 4 + j2;
        float val = acc[m][n][j2];
        if (AFF) val = rs4[j2] * val - rm4[j2] * s_c + t_c;
        C[(size_t)row * HD + col] = f2bf(val);
      }
    }
  }
}

// ------------- transpose-cast: Wt[512,K] = f2bf(ln[k] * W[K,512]^T) ---------
__global__ __launch_bounds__(256) void tcast_kernel(const float* __restrict__ W,
    const float* __restrict__ ln, unsigned short* __restrict__ Wt, int K) {
  __shared__ float t[32][33];
  int n0 = blockIdx.x * 32, k0 = blockIdx.y * 32;
  int c = threadIdx.x & 31, rr = threadIdx.x >> 5;
#pragma unroll
  for (int i = 0; i < 4; ++i) {
    int row = rr + i * 8;
    t[row][c] = W[(size_t)(k0 + row) * HD + n0 + c];
  }
  __syncthreads();
  float lf = ln ? ln[k0 + c] : 1.0f;
#pragma unroll
  for (int i = 0; i < 4; ++i) {
    int row = rr + i * 8;
    Wt[(size_t)(n0 + row) * K + k0 + c] = f2bf(lf * t[c][row]);
  }
}

// ------- colsum: st[n] = sum_k bf(lnw[k]*W[k,n]); st[512+n] = sum lnb[k]*W[k,n]
__global__ __launch_bounds__(512) void colsum_kernel(const float* __restrict__ W,
    const float* __restrict__ lnw, const float* __restrict__ lnb,
    float* __restrict__ st) {
  int c = threadIdx.x & 63, kq = threadIdx.x >> 6;
  int n = blockIdx.x * 64 + c;
  float s = 0.f, t = 0.f;
  for (int k = kq * 64; k < kq * 64 + 64; ++k) {
    float w = W[(size_t)k * HD + n];
    s += bf2f(f2bf(lnw[k] * w));
    t += lnb[k] * w;
  }
  __shared__ float sr[8][64], tr_[8][64];
  sr[kq][c] = s; tr_[kq][c] = t;
  __syncthreads();
  if (kq == 0) {
    for (int q = 1; q < 8; ++q) { s += sr[q][c]; t += tr_[q][c]; }
    st[n] = s; st[512 + n] = t;
  }
}

// ---------------- small fp32 GEMM (final linear only) -----------------------
__global__ __launch_bounds__(256) void gemm64(const float* __restrict__ A,
    const float* __restrict__ B, const float* __restrict__ bias,
    float* __restrict__ C, int M, int N, int K) {
  __shared__ float As[16][68];
  __shared__ float Bs[16][68];
  const int tid = threadIdx.x;
  const int bm = blockIdx.y, bn = blockIdx.x;
  const int tx = tid & 15, ty = tid >> 4;
  const int la_m = tid >> 2, la_k = (tid & 3) << 2;
  const int lb_k = tid >> 4, lb_n = (tid & 15) << 2;
  const float* Ab = A + (size_t)bm * 64 * K;
  const float* Bb = B + bn * 64;
  float acc[4][4] = {};
  for (int k0 = 0; k0 < K; k0 += 16) {
    float4 av = *(const float4*)(Ab + (size_t)la_m * K + k0 + la_k);
    float4 bv = *(const float4*)(Bb + (size_t)(k0 + lb_k) * N + lb_n);
    __syncthreads();
    As[la_k + 0][la_m] = av.x; As[la_k + 1][la_m] = av.y;
    As[la_k + 2][la_m] = av.z; As[la_k + 3][la_m] = av.w;
    *(float4*)&Bs[lb_k][lb_n] = bv;
    __syncthreads();
#pragma unroll
    for (int k = 0; k < 16; ++k) {
      float a0 = As[k][ty * 4 + 0], a1 = As[k][ty * 4 + 1];
      float a2 = As[k][ty * 4 + 2], a3 = As[k][ty * 4 + 3];
      float b0 = Bs[k][tx * 4 + 0], b1 = Bs[k][tx * 4 + 1];
      float b2 = Bs[k][tx * 4 + 2], b3 = Bs[k][tx * 4 + 3];
      acc[0][0] += a0 * b0; acc[0][1] += a0 * b1; acc[0][2] += a0 * b2; acc[0][3] += a0 * b3;
      acc[1][0] += a1 * b0; acc[1][1] += a1 * b1; acc[1][2] += a1 * b2; acc[1][3] += a1 * b3;
      acc[2][0] += a2 * b0; acc[2][1] += a2 * b1; acc[2][2] += a2 * b2; acc[2][3] += a2 * b3;
      acc[3][0] += a3 * b0; acc[3][1] += a3 * b1; acc[3][2] += a3 * b2; acc[3][3] += a3 * b3;
    }
  }
  const int col = bn * 64 + tx * 4;
  float4 bv = make_float4(0.f, 0.f, 0.f, 0.f);
  if (bias) bv = *(const float4*)(bias + col);
#pragma unroll
  for (int i = 0; i < 4; ++i) {
    size_t row = (size_t)bm * 64 + ty * 4 + i;
    float4 v = make_float4(acc[i][0] + bv.x, acc[i][1] + bv.y,
                           acc[i][2] + bv.z, acc[i][3] + bv.w);
    *(float4*)(C + row * N + col) = v;
  }
}

// ------------- rowdot: out[n] = dot(x[n, 0:K], w[0:K]) ----------------------
__global__ __launch_bounds__(256) void rowdot_kernel(const float* __restrict__ x,
    const float* __restrict__ w, float* __restrict__ out, int N, int K) {
  int row = blockIdx.x * 4 + (threadIdx.x >> 6);
  if (row >= N) return;
  int lane = threadIdx.x & 63;
  const float* xp = x + (size_t)row * K;
  float p = 0.f;
  for (int k = lane; k < K; k += 64) p += xp[k] * w[k];
  for (int off = 32; off; off >>= 1) p += __shfl_down(p, off);
  if (lane == 0) out[row] = p;
}

// ----------------------- CSR build ------------------------------------------
__global__ __launch_bounds__(256) void deg_kernel(const int* __restrict__ dst,
    int* __restrict__ deg, int E) {
  int e = blockIdx.x * 256 + threadIdx.x;
  if (e < E) atomicAdd(deg + dst[e], 1);
}

__global__ __launch_bounds__(256) void scan1_kernel(const int* __restrict__ deg,
    int* __restrict__ bsum, int n) {
  __shared__ int sh[4];
  int b = blockIdx.x, tid = threadIdx.x;
  int lane = tid & 63, wid = tid >> 6;
  int v = 0;
#pragma unroll
  for (int j = 0; j < 4; ++j) {
    int i = b * 1024 + j * 256 + tid;
    if (i < n) v += deg[i];
  }
  for (int off = 32; off; off >>= 1) v += __shfl_down(v, off);
  if (lane == 0) sh[wid] = v;
  __syncthreads();
  if (tid == 0) bsum[b] = sh[0] + sh[1] + sh[2] + sh[3];
}

__global__ __launch_bounds__(64) void scan2_kernel(int* __restrict__ bsum, int nb,
    int* __restrict__ rp_end) {
  int tid = threadIdx.x;
  int v = (tid < nb) ? bsum[tid] : 0;
  int x = v;
#pragma unroll
  for (int off = 1; off < 64; off <<= 1) {
    int y = __shfl_up(x, off);
    if (tid >= off) x += y;
  }
  if (tid < nb) bsum[tid] = x - v;
  if (tid == 63) *rp_end = x;
}

__global__ __launch_bounds__(256) void scan3_kernel(const int* __restrict__ deg,
    const int* __restrict__ bsum, int* __restrict__ rp, int n) {
  __shared__ int wsum[4];
  int b = blockIdx.x, tid = threadIdx.x;
  int lane = tid & 63, wid = tid >> 6;
  int carry = bsum[b];
#pragma unroll
  for (int c = 0; c < 4; ++c) {
    int i = b * 1024 + c * 256 + tid;
    int v = (i < n) ? deg[i] : 0;
    int x = v;
#pragma unroll
    for (int off = 1; off < 64; off <<= 1) {
      int y = __shfl_up(x, off);
      if (lane >= off) x += y;
    }
    if (lane == 63) wsum[wid] = x;
    __syncthreads();
    int woff = 0;
    for (int k = 0; k < wid; ++k) woff += wsum[k];
    if (i < n) rp[i] = carry + woff + x - v;
    carry += wsum[0] + wsum[1] + wsum[2] + wsum[3];
    __syncthreads();
  }
}

__global__ __launch_bounds__(256) void copy_kernel(const int* __restrict__ a,
    int* __restrict__ b, int n) {
  int i = blockIdx.x * 256 + threadIdx.x;
  if (i < n) b[i] = a[i];
}

__global__ __launch_bounds__(256) void fill_kernel(const int* __restrict__ dst,
    int* __restrict__ cursor, int* __restrict__ eidx, int E) {
  int e = blockIdx.x * 256 + threadIdx.x;
  if (e >= E) return;
  int pos = atomicAdd(cursor + dst[e], 1);
  eidx[pos] = e;
}

// ---- u-vectors + scalars for logit-dot fusion ------------------------------
__global__ __launch_bounds__(512) void uvec_kernel(const float* __restrict__ wsa_all,
    const float* __restrict__ wda_all,
    const float* __restrict__ ln_v_w, const float* __restrict__ ln_v_b,
    const float* __restrict__ ln_a_w, const float* __restrict__ ln_a_b,
    float* __restrict__ u_v, float* __restrict__ u_a, float* __restrict__ cc) {
  int b = blockIdx.x, tr = b >> 1, side = b & 1;
  int c = threadIdx.x;
  const float* d  = side ? wda_all + (tr + 1) * 512 : wsa_all + (tr + 1) * 1024;
  const float* lw = side ? ln_a_w + tr * HD : ln_v_w + tr * HD;
  const float* lb = side ? ln_a_b + tr * HD : ln_v_b + tr * HD;
  float dv = d[c];
  float uu = lw[c] * dv;
  float bv = lb[c] * dv;
  (side ? u_a : u_v)[tr * 512 + c] = uu;
  for (int off = 32; off; off >>= 1) { uu += __shfl_down(uu, off); bv += __shfl_down(bv, off); }
  __shared__ float s1[8], s2[8];
  int lane = c & 63, wid = c >> 6;
  if (lane == 0) { s1[wid] = uu; s2[wid] = bv; }
  __syncthreads();
  if (c == 0) {
    float a = 0, bb = 0;
    for (int i = 0; i < 8; ++i) { a += s1[i]; bb += s2[i]; }
    cc[tr * 4 + side * 2] = a;
    cc[tr * 4 + side * 2 + 1] = bb;
  }
}

__global__ __launch_bounds__(256) void initab_kernel(float* __restrict__ Av,
    float* __restrict__ Bv, float* __restrict__ Aa, float* __restrict__ Ba) {
  int i = blockIdx.x * 256 + threadIdx.x;
  if (i < NB) { Av[i] = 1.f; Bv[i] = 0.f; Aa[i] = 1.f; Ba[i] = 0.f; }
}

// ---- edge accumulation (shfl-batched CSR walk, bf16 messages) --------------
__device__ inline void acc_edges(const unsigned short* __restrict__ h,
    const int* __restrict__ rp, const int* __restrict__ eidx,
    const int* __restrict__ esrc, const float* __restrict__ ew,
    int d, int lane, float4& a0, float4& a1) {
  int beg = rp[d], end = rp[d + 1];
  for (int base = beg; base < end; base += 64) {
    int cnt = end - base; if (cnt > 64) cnt = 64;
    int s = 0; float w = 0.f;
    if (lane < cnt) {
      int e = eidx[base + lane];
      s = esrc[e];
      w = ew[e];
    }
    for (int j = 0; j < cnt; ++j) {
      int sj = __shfl(s, j);
      float wj = __shfl(w, j);
      ushort8 hv = *(const ushort8*)(h + (size_t)sj * HD + lane * 8);
      a0.x += wj * bf2f(hv[0]); a0.y += wj * bf2f(hv[1]);
      a0.z += wj * bf2f(hv[2]); a0.w += wj * bf2f(hv[3]);
      a1.x += wj * bf2f(hv[4]); a1.y += wj * bf2f(hv[5]);
      a1.z += wj * bf2f(hv[6]); a1.w += wj * bf2f(hv[7]);
    }
  }
}

// ---- merged gather: aa GCN + inline-softmax va GAT + vv GCN ----------------
__global__ __launch_bounds__(256) void gather_all(
    const unsigned short* __restrict__ S_a, const unsigned short* __restrict__ S_s,
    const unsigned short* __restrict__ S_v,
    const int* __restrict__ rp_aa, const int* __restrict__ ex_aa, const int* __restrict__ ei_aa,
    const float* __restrict__ ew_aa,
    const int* __restrict__ rp_va, const int* __restrict__ ex_va, const int* __restrict__ ei_va,
    const int* __restrict__ rp_vv, const int* __restrict__ ex_vv, const int* __restrict__ ei_vv,
    const float* __restrict__ ew_vv,
    const float* __restrict__ b_aa, const float* __restrict__ b_gat,
    const float* __restrict__ b_vv,
    const float* __restrict__ tv_cur, const float* __restrict__ ta_cur,
    const float* __restrict__ Av, const float* __restrict__ Bv,
    const float* __restrict__ Aa, const float* __restrict__ Ba,
    const float* __restrict__ u_v, const float* __restrict__ u_a,
    float* __restrict__ tv_next, float* __restrict__ ta_next,
    float* __restrict__ Q, float* __restrict__ P,
    float* __restrict__ psum, float* __restrict__ psq, int cdots) {
  int blk = blockIdx.x;
  int wv = threadIdx.x >> 6;
  int idx = blk * 4 + wv;
  int lane = threadIdx.x & 63;
  float4 a0, a1;
  bool audio = idx < NA;
  if (audio) {
    a0 = *(const float4*)(b_aa + lane * 8);
    a1 = *(const float4*)(b_aa + lane * 8 + 4);
    float4 c0 = *(const float4*)(b_gat + lane * 8);
    float4 c1 = *(const float4*)(b_gat + lane * 8 + 4);
    a0.x += c0.x; a0.y += c0.y; a0.z += c0.z; a0.w += c0.w;
    a1.x += c1.x; a1.y += c1.y; a1.z += c1.z; a1.w += c1.w;
    acc_edges(S_a, rp_aa, ex_aa, ei_aa, ew_aa, idx, lane, a0, a1);
    int beg = rp_va[idx], end = rp_va[idx + 1];
    if (end > beg) {
      int gd = idx / 100;
      float ld = Aa[gd] * ta_cur[idx] + Ba[gd];
      float ssum = 0.f;
      for (int base = beg; base < end; base += 64) {
        int cnt = end - base; if (cnt > 64) cnt = 64;
        float ex = 0.f;
        if (lane < cnt) {
          int e = ex_va[base + lane];
          int s = ei_va[e];
          int gs = s / 40;
          float l = Av[gs] * tv_cur[s] + Bv[gs] + ld;
          l = (l > 0.f) ? l : 0.2f * l;
          ex = __expf(l);
        }
        float t = ex;
        for (int off = 32; off; off >>= 1) t += __shfl_down(t, off);
        ssum += __shfl(t, 0);
      }
      float inv = 1.f / ssum;
      for (int base = beg; base < end; base += 64) {
        int cnt = end - base; if (cnt > 64) cnt = 64;
        int s = 0; float ex = 0.f;
        if (lane < cnt) {
          int e = ex_va[base + lane];
          s = ei_va[e];
          int gs = s / 40;
          float l = Av[gs] * tv_cur[s] + Bv[gs] + ld;
          l = (l > 0.f) ? l : 0.2f * l;
          ex = __expf(l);
        }
        for (int j = 0; j < cnt; ++j) {
          int sj = __shfl(s, j);
          float wj = __shfl(ex, j) * inv;
          ushort8 hv = *(const ushort8*)(S_s + (size_t)sj * HD + lane * 8);
          a0.x += wj * bf2f(hv[0]); a0.y += wj * bf2f(hv[1]);
          a0.z += wj * bf2f(hv[2]); a0.w += wj * bf2f(hv[3]);
          a1.x += wj * bf2f(hv[4]); a1.y += wj * bf2f(hv[5]);
          a1.z += wj * bf2f(hv[6]); a1.w += wj * bf2f(hv[7]);
        }
      }
    }
    float* op = Q + (size_t)idx * HD + lane * 8;
    *(float4*)(op) = a0;
    *(float4*)(op + 4) = a1;
  } else {
    int d = idx - NA;
    a0 = *(const float4*)(b_vv + lane * 8);
    a1 = *(const float4*)(b_vv + lane * 8 + 4);
    acc_edges(S_v, rp_vv, ex_vv, ei_vv, ew_vv, d, lane, a0, a1);
    float* op = P + (size_t)d * HD + lane * 8;
    *(float4*)(op) = a0;
    *(float4*)(op + 4) = a1;
  }
  float rs = 0.f, rq = 0.f;
#define RELQ(x) { float v_ = fmaxf(x, 0.f); rs += v_; rq += v_ * v_; }
  RELQ(a0.x) RELQ(a0.y) RELQ(a0.z) RELQ(a0.w)
  RELQ(a1.x) RELQ(a1.y) RELQ(a1.z) RELQ(a1.w)
#undef RELQ
  float rs2 = rs, rq2 = rq;
  for (int off = 32; off; off >>= 1) {
    rs2 += __shfl_down(rs2, off);
    rq2 += __shfl_down(rq2, off);
  }
  __shared__ float bs[4], bq[4];
  if (lane == 0) { bs[wv] = rs2; bq[wv] = rq2; }
  if (cdots) {
    const float* u = audio ? u_a : u_v;
    float4 u0 = *(const float4*)(u + lane * 8);
    float4 u1 = *(const float4*)(u + lane * 8 + 4);
    float tn = u0.x * fmaxf(a0.x, 0.f) + u0.y * fmaxf(a0.y, 0.f)
             + u0.z * fmaxf(a0.z, 0.f) + u0.w * fmaxf(a0.w, 0.f)
             + u1.x * fmaxf(a1.x, 0.f) + u1.y * fmaxf(a1.y, 0.f)
             + u1.z * fmaxf(a1.z, 0.f) + u1.w * fmaxf(a1.w, 0.f);
    for (int off = 32; off; off >>= 1) tn += __shfl_down(tn, off);
    if (lane == 0) {
      if (audio) ta_next[idx] = tn;
      else       tv_next[idx - NA] = tn;
    }
  }
  __syncthreads();
  if (threadIdx.x == 0) {
    psum[blk] = bs[0] + bs[1] + bs[2] + bs[3];
    psq[blk]  = bq[0] + bq[1] + bq[2] + bq[3];
  }
}

// ---- finalize: per-graph mean/rstd (+ next-layer logit affine A,B) ---------
__global__ __launch_bounds__(256) void finalize_kernel(const float* __restrict__ psum,
    const float* __restrict__ psq,
    float* __restrict__ mean_a, float* __restrict__ rstd_a,
    float* __restrict__ mean_v, float* __restrict__ rstd_v,
    float* __restrict__ Aa, float* __restrict__ Ba,
    float* __restrict__ Av, float* __restrict__ Bv,
    const float* __restrict__ cc, int tr, int wnext) {
  int i = blockIdx.x * 256 + threadIdx.x;
  if (i >= 2 * NB) return;
  bool aud = i < NB;
  int g = aud ? i : i - NB;
  int pbase = aud ? g * 25 : ABLK + g * 10;
  int pcnt = aud ? 25 : 10;
  float s = 0.f, q = 0.f;
  for (int k = 0; k < pcnt; ++k) { s += psum[pbase + k]; q += psq[pbase + k]; }
  float M = aud ? 100.f * 512.f : 40.f * 512.f;
  float mean = s / M;
  float var = q / M - mean * mean;
  float rstd = rsqrtf(fmaxf(var, 0.f) + 1e-5f);
  if (aud) { mean_a[g] = mean; rstd_a[g] = rstd; }
  else     { mean_v[g] = mean; rstd_v[g] = rstd; }
  if (wnext) {
    float c1 = cc[tr * 4 + (aud ? 2 : 0)];
    float c2 = cc[tr * 4 + (aud ? 2 : 0) + 1];
    float A = rstd, B = -rstd * mean * c1 + c2;
    if (aud) { Aa[g] = A; Ba[g] = B; }
    else     { Av[g] = A; Bv[g] = B; }
  }
}

// ------- readout with inline final-layer norm affine ------------------------
__global__ __launch_bounds__(512) void readout_kernel(const float* __restrict__ xa,
    const float* __restrict__ att_w,
    const float* __restrict__ mean_a, const float* __restrict__ rstd_a,
    const float* __restrict__ lw, const float* __restrict__ lb,
    float* __restrict__ ge) {
  int g = blockIdx.x;
  int tid = threadIdx.x;
  int lane = tid & 63, wid = tid >> 6;
  const float* xg = xa + (size_t)g * 100 * HD;
  float mean = mean_a[g], rstd = rstd_a[g];
  __shared__ float gv[112];
  for (int n = wid; n < 100; n += 8) {
    float p = 0.f;
#pragma unroll
    for (int j = 0; j < 8; ++j) {
      int c = j * 64 + lane;
      float o = lw[c] * (fmaxf(xg[(size_t)n * HD + c], 0.f) - mean) * rstd + lb[c];
      p += o * att_w[c];
    }
    for (int off = 32; off; off >>= 1) p += __shfl_down(p, off);
    if (lane == 0) gv[n] = p;
  }
  __syncthreads();
  __shared__ float inv_s;
  if (tid == 0) {
    float m = -1e30f;
    for (int n = 0; n < 100; ++n) m = fmaxf(m, gv[n]);
    float ssum = 0.f;
    for (int n = 0; n < 100; ++n) { float e = __expf(gv[n] - m); gv[n] = e; ssum += e; }
    inv_s = 1.0f / fmaxf(ssum, 1e-16f);
  }
  __syncthreads();
  float inv = inv_s;
  float wwc = lw[tid], bbc = lb[tid];
  float acc = 0.f;
  for (int n = 0; n < 100; ++n) {
    float o = wwc * (fmaxf(xg[(size_t)n * HD + tid], 0.f) - mean) * rstd + bbc;
    acc += gv[n] * o;
  }
  ge[(size_t)g * HD + tid] = acc * inv;
}

// ----------------------------------------------------------------------------
extern "C" void kernel_launch(void* const* d_in, const int* in_sizes, int n_in,
                              void* d_out, int out_size, void* d_ws, size_t ws_size,
                              hipStream_t stream) {
  const float* x_video = (const float*)d_in[0];
  const float* x_audio = (const float*)d_in[1];
  const float* ew_vv   = (const float*)d_in[2];
  const float* ew_aa   = (const float*)d_in[3];
  const float* W_vv0   = (const float*)d_in[4];
  const float* W_aa0   = (const float*)d_in[5];
  const float* W_src0  = (const float*)d_in[6];
  const float* W_dst0  = (const float*)d_in[7];
  const float* W_vv    = (const float*)d_in[8];
  const float* W_aa    = (const float*)d_in[9];
  const float* W_src   = (const float*)d_in[10];
  const float* W_dst   = (const float*)d_in[11];
  const float* b_vv    = (const float*)d_in[12];
  const float* b_aa    = (const float*)d_in[13];
  const float* b_gat   = (const float*)d_in[14];
  const float* a_src   = (const float*)d_in[15];
  const float* a_dst   = (const float*)d_in[16];
  const float* ln_v_w  = (const float*)d_in[17];
  const float* ln_v_b  = (const float*)d_in[18];
  const float* ln_a_w  = (const float*)d_in[19];
  const float* ln_a_b  = (const float*)d_in[20];
  const float* att_w   = (const float*)d_in[21];
  const float* lin_W   = (const float*)d_in[22];
  const float* lin_b   = (const float*)d_in[23];
  const int*   ei_vv   = (const int*)d_in[24];
  const int*   ei_aa   = (const int*)d_in[25];
  const int*   ei_va   = (const int*)d_in[26];

  // ---- workspace carve-up (4B units) ----
  const size_t WT_ELEMS = (size_t)HD * DV;
  const size_t REQ = (size_t)NV * HD + (size_t)NA * HD
                   + (size_t)NA * HD / 2 + (size_t)NV * HD
                   + 2 * NV + 2 * NA + 4096 + 2048 + 3 * 512 * 2 + 16
                   + 8 * NB + 2 * GBLK + (size_t)NB * HD + 9 * 1024
                   + (NV + 1) + EVV + (NA + 1) + EAA + (NA + 1) + EVA
                   + 3 * (WT_ELEMS / 2) + 64;
  if (ws_size < REQ * sizeof(float)) return;

  float* p = (float*)d_ws;
  float* P  = p; p += (size_t)NV * HD;
  float* Q  = p; p += (size_t)NA * HD;
  unsigned short* S_a = (unsigned short*)p; p += (size_t)NA * HD / 2;
  unsigned short* S_s = (unsigned short*)p; p += (size_t)NV * HD / 2;
  unsigned short* S_v = (unsigned short*)p; p += (size_t)NV * HD / 2;
  float* tv0 = p; p += NV;
  float* tv1 = p; p += NV;
  float* ta0 = p; p += NA;
  float* ta1 = p; p += NA;
  float* wsa_all = p; p += 4096;        // [4][1024]
  float* wda_all = p; p += 2048;        // [4][512]
  float* u_v = p; p += 3 * 512;
  float* u_a = p; p += 3 * 512;
  float* cc  = p; p += 16;
  float* mean_a = p; p += NB;
  float* rstd_a = p; p += NB;
  float* mean_v = p; p += NB;
  float* rstd_v = p; p += NB;
  float* Aa = p; p += NB;
  float* Ba = p; p += NB;
  float* Av = p; p += NB;
  float* Bv = p; p += NB;
  float* psum = p; p += GBLK;
  float* psq  = p; p += GBLK;
  float* ge   = p; p += (size_t)NB * HD;
  float* st_all = p; p += 9 * 1024;     // [tr][mat: s,v,a][s|t][512]
  int* rp_vv = (int*)p; p += NV + 1;
  int* ex_vv = (int*)p; p += EVV;
  int* rp_aa = (int*)p; p += NA + 1;
  int* ex_aa = (int*)p; p += EAA;
  int* rp_va = (int*)p; p += NA + 1;
  int* ex_va = (int*)p; p += EVA;
  unsigned short* Wt_v = (unsigned short*)p; p += WT_ELEMS / 2;
  unsigned short* Wt_a = (unsigned short*)p; p += WT_ELEMS / 2;
  unsigned short* Wt_s = (unsigned short*)p; p += WT_ELEMS / 2;
  int* bsum = (int*)p; p += 64;

  int* degbuf = (int*)ta0;   // NA ints; dead before rowdots write ta0
  int* curbuf = (int*)ta1;   // NA ints

  // ---- build CSR (once) ----
  {
    struct { const int* dst; int* rp; int* ex; int N; int E; } g[3] = {
      { ei_vv + EVV, rp_vv, ex_vv, NV, EVV },
      { ei_aa + EAA, rp_aa, ex_aa, NA, EAA },
      { ei_va + EVA, rp_va, ex_va, NA, EVA },
    };
    for (int i = 0; i < 3; ++i) {
      int nb = (g[i].N + 1023) / 1024;
      hipMemsetAsync(degbuf, 0, (size_t)g[i].N * sizeof(int), stream);
      deg_kernel<<<(g[i].E + 255) / 256, 256, 0, stream>>>(g[i].dst, degbuf, g[i].E);
      scan1_kernel<<<nb, 256, 0, stream>>>(degbuf, bsum, g[i].N);
      scan2_kernel<<<1, 64, 0, stream>>>(bsum, nb, g[i].rp + g[i].N);
      scan3_kernel<<<nb, 256, 0, stream>>>(degbuf, bsum, g[i].rp, g[i].N);
      copy_kernel<<<(g[i].N + 255) / 256, 256, 0, stream>>>(g[i].rp, curbuf, g[i].N);
      fill_kernel<<<(g[i].E + 255) / 256, 256, 0, stream>>>(g[i].dst, curbuf, g[i].ex, g[i].E);
    }
  }

  // ---- prologue: logit-dot vectors, layer-0 dots, colsums ----
  for (int i = 0; i < NL; ++i) {
    const int Kv = (i == 0) ? DV : HD;
    const int Ka = (i == 0) ? DA : HD;
    const float* Ws = (i == 0) ? W_src0 : W_src + (size_t)(i - 1) * HD * HD;
    const float* Wd = (i == 0) ? W_dst0 : W_dst + (size_t)(i - 1) * HD * HD;
    rowdot_kernel<<<(Ka + 3) / 4, 256, 0, stream>>>(Wd, a_dst + i * HD, wda_all + i * 512, Ka, HD);
    rowdot_kernel<<<(Kv + 3) / 4, 256, 0, stream>>>(Ws, a_src + i * HD, wsa_all + i * 1024, Kv, HD);
  }
  rowdot_kernel<<<NA / 4, 256, 0, stream>>>(x_audio, wda_all, ta0, NA, DA);
  rowdot_kernel<<<NV / 4, 256, 0, stream>>>(x_video, wsa_all, tv0, NV, DV);
  uvec_kernel<<<6, 512, 0, stream>>>(wsa_all, wda_all, ln_v_w, ln_v_b, ln_a_w, ln_a_b,
                                     u_v, u_a, cc);
  initab_kernel<<<(NB + 255) / 256, 256, 0, stream>>>(Av, Bv, Aa, Ba);
  for (int tr = 0; tr < 3; ++tr) {
    const float* lvw = ln_v_w + tr * HD; const float* lvb = ln_v_b + tr * HD;
    const float* law = ln_a_w + tr * HD; const float* lab = ln_a_b + tr * HD;
    colsum_kernel<<<8, 512, 0, stream>>>(W_src + (size_t)tr * HD * HD, lvw, lvb, st_all + (tr * 3 + 0) * 1024);
    colsum_kernel<<<8, 512, 0, stream>>>(W_vv  + (size_t)tr * HD * HD, lvw, lvb, st_all + (tr * 3 + 1) * 1024);
    colsum_kernel<<<8, 512, 0, stream>>>(W_aa  + (size_t)tr * HD * HD, law, lab, st_all + (tr * 3 + 2) * 1024);
  }

  const float* xv_cur = x_video;
  const float* xa_cur = x_audio;
  float* tv_cur = tv0; float* tv_nxt = tv1;
  float* ta_cur = ta0; float* ta_nxt = ta1;

  for (int i = 0; i < NL; ++i) {
    const int Kv = (i == 0) ? DV : HD;
    const int Ka = (i == 0) ? DA : HD;
    const float* Wv = (i == 0) ? W_vv0  : W_vv  + (size_t)(i - 1) * HD * HD;
    const float* Wa = (i == 0) ? W_aa0  : W_aa  + (size_t)(i - 1) * HD * HD;
    const float* Ws = (i == 0) ? W_src0 : W_src + (size_t)(i - 1) * HD * HD;
    const float* lnv_prev = (i == 0) ? nullptr : ln_v_w + (size_t)(i - 1) * HD;
    const float* lna_prev = (i == 0) ? nullptr : ln_a_w + (size_t)(i - 1) * HD;

    // weights folded with prev-layer ln_w (W' = diag(lnw) W), cast to bf16
    tcast_kernel<<<dim3(HD / 32, Kv / 32), 256, 0, stream>>>(Wv, lnv_prev, Wt_v, Kv);
    tcast_kernel<<<dim3(HD / 32, Ka / 32), 256, 0, stream>>>(Wa, lna_prev, Wt_a, Ka);
    tcast_kernel<<<dim3(HD / 32, Kv / 32), 256, 0, stream>>>(Ws, lnv_prev, Wt_s, Kv);

    if (i == 0)
      mfma_gemm3<0><<<GTOT, 256, 0, stream>>>(xv_cur, xa_cur, Wt_s, Wt_v, Wt_a,
          S_s, S_v, S_a, Kv, Ka,
          nullptr, nullptr, nullptr, nullptr, nullptr, nullptr, nullptr);
    else {
      const float* stb = st_all + (size_t)(i - 1) * 3 * 1024;
      mfma_gemm3<1><<<GTOT, 256, 0, stream>>>(xv_cur, xa_cur, Wt_s, Wt_v, Wt_a,
          S_s, S_v, S_a, Kv, Ka,
          mean_v, rstd_v, mean_a, rstd_a,
          stb, stb + 1024, stb + 2048);
    }

    int cdots = (i + 1 < NL) ? 1 : 0;
    gather_all<<<GBLK, 256, 0, stream>>>(S_a, S_s, S_v,
        rp_aa, ex_aa, ei_aa, ew_aa, rp_va, ex_va, ei_va,
        rp_vv, ex_vv, ei_vv, ew_vv,
        b_aa + i * HD, b_gat + i * HD, b_vv + i * HD,
        tv_cur, ta_cur, Av, Bv, Aa, Ba,
        u_v + i * 512, u_a + i * 512,
        tv_nxt, ta_nxt, Q, P, psum, psq, cdots);

    finalize_kernel<<<(2 * NB + 255) / 256, 256, 0, stream>>>(psum, psq,
        mean_a, rstd_a, mean_v, rstd_v, Aa, Ba, Av, Bv, cc, i, cdots);

    xv_cur = P;
    xa_cur = Q;
    float* t;
    t = tv_cur; tv_cur = tv_nxt; tv_nxt = t;
    t = ta_cur; ta_cur = ta_nxt; ta_nxt = t;
  }

  // ---- readout (inline final norm affine) + final linear ----
  readout_kernel<<<NB, 512, 0, stream>>>(Q, att_w, mean_a, rstd_a,
      ln_a_w + (NL - 1) * HD, ln_a_b + (NL - 1) * HD, ge);
  gemm64<<<dim3(NOUT / 64, NB / 64), 256, 0, stream>>>(ge, lin_W, lin_b, (float*)d_out, NB, NOUT, HD);
}

// Round 14
// 1207.007 us; speedup vs baseline: 1.2601x; 1.2601x over previous
//
#include <hip/hip_runtime.h>

#define NB   512
#define NV   20480
#define NA   51200
#define EVV  163840
#define EAA  409600
#define EVA  61440
#define DV   1024
#define DA   128
#define HD   512
#define NOUT 128
#define NL   4

#define VTILES 160           // NV/128
#define ATILES 400           // NA/128
#define GSEC0  (VTILES * 4)  // 640  (hs)
#define GSEC1  (GSEC0 * 2)   // 1280 (hv)
#define GTOT   (GSEC1 + ATILES * 4)  // 2880
#define ABLK   (NA / 4)      // 12800 audio gather blocks
#define GBLK   ((NA + NV) / 4)

typedef __attribute__((ext_vector_type(8))) short short8;
typedef __attribute__((ext_vector_type(8))) unsigned short ushort8;
typedef __attribute__((ext_vector_type(4))) float f32x4;

__device__ inline unsigned short f2bf(float f) {
  unsigned u = __float_as_uint(f);
  return (unsigned short)((u + 0x7fffu + ((u >> 16) & 1u)) >> 16);
}
__device__ inline float bf2f(unsigned short h) {
  return __uint_as_float((unsigned)h << 16);
}

// ---- merged MFMA GEMM; AFF=0: fp32 A (layer 0), AFF=1: bf16 A (pure copy) --
// sections: [0,640) hs, [640,1280) hv, [1280,2880) ha.
// AFF=1 epilogue: h = rstd*acc - rstd*mean*s[col] + t[col].
template <int AFF>
__global__ __launch_bounds__(256) void mfma_gemm3(const void* __restrict__ xvp,
    const void* __restrict__ xap,
    const unsigned short* __restrict__ Wt_s, const unsigned short* __restrict__ Wt_v,
    const unsigned short* __restrict__ Wt_a,
    unsigned short* __restrict__ S_s, unsigned short* __restrict__ S_v,
    unsigned short* __restrict__ S_a, int Kv, int Ka,
    const float* __restrict__ mean_v, const float* __restrict__ rstd_v,
    const float* __restrict__ mean_a, const float* __restrict__ rstd_a,
    const float* __restrict__ st_s, const float* __restrict__ st_v,
    const float* __restrict__ st_a) {
  __shared__ unsigned short As[128 * 40];
  __shared__ unsigned short Bs[128 * 40];
  const int id = blockIdx.x;
  const void* Ap; const unsigned short* Bt; unsigned short* C; int K; int lid;
  const float* stp; bool video;
  if (id < GSEC0)      { Ap = xvp; Bt = Wt_s; C = S_s; K = Kv; lid = id; stp = st_s; video = true; }
  else if (id < GSEC1) { Ap = xvp; Bt = Wt_v; C = S_v; K = Kv; lid = id - GSEC0; stp = st_v; video = true; }
  else                 { Ap = xap; Bt = Wt_a; C = S_a; K = Ka; lid = id - GSEC1; stp = st_a; video = false; }
  const int xcd = lid & 7;
  const int j = lid >> 3;
  const int bn = j & 3;
  const int bm = xcd + ((j >> 2) << 3);
  const int tid = threadIdx.x;
  const int l = tid & 63, wid = tid >> 6;
  const int wr = wid >> 1, wc = wid & 1;
  const int r = tid >> 1;
  const int kh = (tid & 1) << 4;

  const unsigned short* btp = Bt + (size_t)(bn * 128 + r) * K + kh;

  f32x4 acc[4][4] = {};
  const int fr = l & 15, fq = l >> 4;
  const int arow = (wr * 64 + fr) * 40 + fq * 8;
  const int brow = (wc * 64 + fr) * 40 + fq * 8;

  if (AFF == 0) {
    // fp32 A with fused cast (raw inputs, layer 0)
    const float* ap = (const float*)Ap + (size_t)(bm * 128 + r) * K + kh;
    for (int k0 = 0; k0 < K; k0 += 32) {
      float4 f0 = *(const float4*)(ap + k0 + 0);
      float4 f1 = *(const float4*)(ap + k0 + 4);
      float4 f2 = *(const float4*)(ap + k0 + 8);
      float4 f3 = *(const float4*)(ap + k0 + 12);
      short8 bv0 = *(const short8*)(btp + k0);
      short8 bv1 = *(const short8*)(btp + k0 + 8);
      short8 p0, p1;
      p0[0] = (short)f2bf(f0.x); p0[1] = (short)f2bf(f0.y);
      p0[2] = (short)f2bf(f0.z); p0[3] = (short)f2bf(f0.w);
      p0[4] = (short)f2bf(f1.x); p0[5] = (short)f2bf(f1.y);
      p0[6] = (short)f2bf(f1.z); p0[7] = (short)f2bf(f1.w);
      p1[0] = (short)f2bf(f2.x); p1[1] = (short)f2bf(f2.y);
      p1[2] = (short)f2bf(f2.z); p1[3] = (short)f2bf(f2.w);
      p1[4] = (short)f2bf(f3.x); p1[5] = (short)f2bf(f3.y);
      p1[6] = (short)f2bf(f3.z); p1[7] = (short)f2bf(f3.w);
      __syncthreads();
      *(short8*)&As[r * 40 + kh] = p0;
      *(short8*)&As[r * 40 + kh + 8] = p1;
      *(short8*)&Bs[r * 40 + kh] = bv0;
      *(short8*)&Bs[r * 40 + kh + 8] = bv1;
      __syncthreads();
      short8 a[4], b[4];
#pragma unroll
      for (int m = 0; m < 4; ++m) a[m] = *(const short8*)&As[arow + m * 16 * 40];
#pragma unroll
      for (int n = 0; n < 4; ++n) b[n] = *(const short8*)&Bs[brow + n * 16 * 40];
#pragma unroll
      for (int m = 0; m < 4; ++m)
#pragma unroll
        for (int n = 0; n < 4; ++n)
          acc[m][n] = __builtin_amdgcn_mfma_f32_16x16x32_bf16(a[m], b[n], acc[m][n], 0, 0, 0);
    }
  } else {
    // bf16 A (relu'd features written by gather) — staging is a pure copy
    const unsigned short* ap = (const unsigned short*)Ap + (size_t)(bm * 128 + r) * K + kh;
    for (int k0 = 0; k0 < K; k0 += 32) {
      short8 av0 = *(const short8*)(ap + k0);
      short8 av1 = *(const short8*)(ap + k0 + 8);
      short8 bv0 = *(const short8*)(btp + k0);
      short8 bv1 = *(const short8*)(btp + k0 + 8);
      __syncthreads();
      *(short8*)&As[r * 40 + kh] = av0;
      *(short8*)&As[r * 40 + kh + 8] = av1;
      *(short8*)&Bs[r * 40 + kh] = bv0;
      *(short8*)&Bs[r * 40 + kh + 8] = bv1;
      __syncthreads();
      short8 a[4], b[4];
#pragma unroll
      for (int m = 0; m < 4; ++m) a[m] = *(const short8*)&As[arow + m * 16 * 40];
#pragma unroll
      for (int n = 0; n < 4; ++n) b[n] = *(const short8*)&Bs[brow + n * 16 * 40];
#pragma unroll
      for (int m = 0; m < 4; ++m)
#pragma unroll
        for (int n = 0; n < 4; ++n)
          acc[m][n] = __builtin_amdgcn_mfma_f32_16x16x32_bf16(a[m], b[n], acc[m][n], 0, 0, 0);
    }
  }

  // epilogue: per-row scalars (rstd, rstd*mean) + per-col (s, t)
#pragma unroll
  for (int m = 0; m < 4; ++m) {
    float rs4[4], rm4[4];
    if (AFF) {
#pragma unroll
      for (int j2 = 0; j2 < 4; ++j2) {
        int row = bm * 128 + wr * 64 + m * 16 + fq * 4 + j2;
        int g = video ? row / 40 : row / 100;
        float rs_ = video ? rstd_v[g] : rstd_a[g];
        float mn_ = video ? mean_v[g] : mean_a[g];
        rs4[j2] = rs_;
        rm4[j2] = rs_ * mn_;
      }
    }
#pragma unroll
    for (int n = 0; n < 4; ++n) {
      int col = bn * 128 + wc * 64 + n * 16 + fr;
      float s_c = 0.f, t_c = 0.f;
      if (AFF) { s_c = stp[col]; t_c = stp[512 + col]; }
#pragma unroll
      for (int j2 = 0; j2 < 4; ++j2) {
        int row = bm * 128 + wr * 64 + m * 16 + fq * 4 + j2;
        float val = acc[m][n][j2];
        if (AFF) val = rs4[j2] * val - rm4[j2] * s_c + t_c;
        C[(size_t)row * HD + col] = f2bf(val);
      }
    }
  }
}

// ------------- transpose-cast: Wt[512,K] = f2bf(ln[k] * W[K,512]^T) ---------
__global__ __launch_bounds__(256) void tcast_kernel(const float* __restrict__ W,
    const float* __restrict__ ln, unsigned short* __restrict__ Wt, int K) {
  __shared__ float t[32][33];
  int n0 = blockIdx.x * 32, k0 = blockIdx.y * 32;
  int c = threadIdx.x & 31, rr = threadIdx.x >> 5;
#pragma unroll
  for (int i = 0; i < 4; ++i) {
    int row = rr + i * 8;
    t[row][c] = W[(size_t)(k0 + row) * HD + n0 + c];
  }
  __syncthreads();
  float lf = ln ? ln[k0 + c] : 1.0f;
#pragma unroll
  for (int i = 0; i < 4; ++i) {
    int row = rr + i * 8;
    Wt[(size_t)(n0 + row) * K + k0 + c] = f2bf(lf * t[c][row]);
  }
}

// ------- merged colsum for all 9 (layer-transition, matrix) pairs -----------
// blockIdx.y: tr*3 + m, m in {0:W_src(v-ln), 1:W_vv(v-ln), 2:W_aa(a-ln)}.
// st[n] = sum_k bf2f(f2bf(lnw[k]*W[k,n])); st[512+n] = sum_k lnb[k]*W[k,n]
__global__ __launch_bounds__(512) void colsum9_kernel(const float* __restrict__ W_src,
    const float* __restrict__ W_vv, const float* __restrict__ W_aa,
    const float* __restrict__ ln_v_w, const float* __restrict__ ln_v_b,
    const float* __restrict__ ln_a_w, const float* __restrict__ ln_a_b,
    float* __restrict__ st_all) {
  int tr = blockIdx.y / 3, m = blockIdx.y % 3;
  const float* W = (m == 0 ? W_src : m == 1 ? W_vv : W_aa) + (size_t)tr * HD * HD;
  const float* lnw = (m == 2 ? ln_a_w : ln_v_w) + tr * HD;
  const float* lnb = (m == 2 ? ln_a_b : ln_v_b) + tr * HD;
  float* st = st_all + (size_t)blockIdx.y * 1024;
  int c = threadIdx.x & 63, kq = threadIdx.x >> 6;
  int n = blockIdx.x * 64 + c;
  float s = 0.f, t = 0.f;
  for (int k = kq * 64; k < kq * 64 + 64; ++k) {
    float w = W[(size_t)k * HD + n];
    s += bf2f(f2bf(lnw[k] * w));
    t += lnb[k] * w;
  }
  __shared__ float sr[8][64], tr_[8][64];
  sr[kq][c] = s; tr_[kq][c] = t;
  __syncthreads();
  if (kq == 0) {
    for (int q = 1; q < 8; ++q) { s += sr[q][c]; t += tr_[q][c]; }
    st[n] = s; st[512 + n] = t;
  }
}

// ---------------- small fp32 GEMM (final linear only) -----------------------
__global__ __launch_bounds__(256) void gemm64(const float* __restrict__ A,
    const float* __restrict__ B, const float* __restrict__ bias,
    float* __restrict__ C, int M, int N, int K) {
  __shared__ float As[16][68];
  __shared__ float Bs[16][68];
  const int tid = threadIdx.x;
  const int bm = blockIdx.y, bn = blockIdx.x;
  const int tx = tid & 15, ty = tid >> 4;
  const int la_m = tid >> 2, la_k = (tid & 3) << 2;
  const int lb_k = tid >> 4, lb_n = (tid & 15) << 2;
  const float* Ab = A + (size_t)bm * 64 * K;
  const float* Bb = B + bn * 64;
  float acc[4][4] = {};
  for (int k0 = 0; k0 < K; k0 += 16) {
    float4 av = *(const float4*)(Ab + (size_t)la_m * K + k0 + la_k);
    float4 bv = *(const float4*)(Bb + (size_t)(k0 + lb_k) * N + lb_n);
    __syncthreads();
    As[la_k + 0][la_m] = av.x; As[la_k + 1][la_m] = av.y;
    As[la_k + 2][la_m] = av.z; As[la_k + 3][la_m] = av.w;
    *(float4*)&Bs[lb_k][lb_n] = bv;
    __syncthreads();
#pragma unroll
    for (int k = 0; k < 16; ++k) {
      float a0 = As[k][ty * 4 + 0], a1 = As[k][ty * 4 + 1];
      float a2 = As[k][ty * 4 + 2], a3 = As[k][ty * 4 + 3];
      float b0 = Bs[k][tx * 4 + 0], b1 = Bs[k][tx * 4 + 1];
      float b2 = Bs[k][tx * 4 + 2], b3 = Bs[k][tx * 4 + 3];
      acc[0][0] += a0 * b0; acc[0][1] += a0 * b1; acc[0][2] += a0 * b2; acc[0][3] += a0 * b3;
      acc[1][0] += a1 * b0; acc[1][1] += a1 * b1; acc[1][2] += a1 * b2; acc[1][3] += a1 * b3;
      acc[2][0] += a2 * b0; acc[2][1] += a2 * b1; acc[2][2] += a2 * b2; acc[2][3] += a2 * b3;
      acc[3][0] += a3 * b0; acc[3][1] += a3 * b1; acc[3][2] += a3 * b2; acc[3][3] += a3 * b3;
    }
  }
  const int col = bn * 64 + tx * 4;
  float4 bv = make_float4(0.f, 0.f, 0.f, 0.f);
  if (bias) bv = *(const float4*)(bias + col);
#pragma unroll
  for (int i = 0; i < 4; ++i) {
    size_t row = (size_t)bm * 64 + ty * 4 + i;
    float4 v = make_float4(acc[i][0] + bv.x, acc[i][1] + bv.y,
                           acc[i][2] + bv.z, acc[i][3] + bv.w);
    *(float4*)(C + row * N + col) = v;
  }
}

// ------------- rowdot: out[n] = dot(x[n, 0:K], w[0:K]) ----------------------
__global__ __launch_bounds__(256) void rowdot_kernel(const float* __restrict__ x,
    const float* __restrict__ w, float* __restrict__ out, int N, int K) {
  int row = blockIdx.x * 4 + (threadIdx.x >> 6);
  if (row >= N) return;
  int lane = threadIdx.x & 63;
  const float* xp = x + (size_t)row * K;
  float p = 0.f;
  for (int k = lane; k < K; k += 64) p += xp[k] * w[k];
  for (int off = 32; off; off >>= 1) p += __shfl_down(p, off);
  if (lane == 0) out[row] = p;
}

// ----------------------- CSR build ------------------------------------------
__global__ __launch_bounds__(256) void deg_kernel(const int* __restrict__ dst,
    int* __restrict__ deg, int E) {
  int e = blockIdx.x * 256 + threadIdx.x;
  if (e < E) atomicAdd(deg + dst[e], 1);
}

__global__ __launch_bounds__(256) void scan1_kernel(const int* __restrict__ deg,
    int* __restrict__ bsum, int n) {
  __shared__ int sh[4];
  int b = blockIdx.x, tid = threadIdx.x;
  int lane = tid & 63, wid = tid >> 6;
  int v = 0;
#pragma unroll
  for (int j = 0; j < 4; ++j) {
    int i = b * 1024 + j * 256 + tid;
    if (i < n) v += deg[i];
  }
  for (int off = 32; off; off >>= 1) v += __shfl_down(v, off);
  if (lane == 0) sh[wid] = v;
  __syncthreads();
  if (tid == 0) bsum[b] = sh[0] + sh[1] + sh[2] + sh[3];
}

__global__ __launch_bounds__(64) void scan2_kernel(int* __restrict__ bsum, int nb,
    int* __restrict__ rp_end) {
  int tid = threadIdx.x;
  int v = (tid < nb) ? bsum[tid] : 0;
  int x = v;
#pragma unroll
  for (int off = 1; off < 64; off <<= 1) {
    int y = __shfl_up(x, off);
    if (tid >= off) x += y;
  }
  if (tid < nb) bsum[tid] = x - v;
  if (tid == 63) *rp_end = x;
}

__global__ __launch_bounds__(256) void scan3_kernel(const int* __restrict__ deg,
    const int* __restrict__ bsum, int* __restrict__ rp, int n) {
  __shared__ int wsum[4];
  int b = blockIdx.x, tid = threadIdx.x;
  int lane = tid & 63, wid = tid >> 6;
  int carry = bsum[b];
#pragma unroll
  for (int c = 0; c < 4; ++c) {
    int i = b * 1024 + c * 256 + tid;
    int v = (i < n) ? deg[i] : 0;
    int x = v;
#pragma unroll
    for (int off = 1; off < 64; off <<= 1) {
      int y = __shfl_up(x, off);
      if (lane >= off) x += y;
    }
    if (lane == 63) wsum[wid] = x;
    __syncthreads();
    int woff = 0;
    for (int k = 0; k < wid; ++k) woff += wsum[k];
    if (i < n) rp[i] = carry + woff + x - v;
    carry += wsum[0] + wsum[1] + wsum[2] + wsum[3];
    __syncthreads();
  }
}

__global__ __launch_bounds__(256) void copy_kernel(const int* __restrict__ a,
    int* __restrict__ b, int n) {
  int i = blockIdx.x * 256 + threadIdx.x;
  if (i < n) b[i] = a[i];
}

__global__ __launch_bounds__(256) void fill_kernel(const int* __restrict__ dst,
    int* __restrict__ cursor, int* __restrict__ eidx, int E) {
  int e = blockIdx.x * 256 + threadIdx.x;
  if (e >= E) return;
  int pos = atomicAdd(cursor + dst[e], 1);
  eidx[pos] = e;
}

// ---- u-vectors + scalars for logit-dot fusion ------------------------------
__global__ __launch_bounds__(512) void uvec_kernel(const float* __restrict__ wsa_all,
    const float* __restrict__ wda_all,
    const float* __restrict__ ln_v_w, const float* __restrict__ ln_v_b,
    const float* __restrict__ ln_a_w, const float* __restrict__ ln_a_b,
    float* __restrict__ u_v, float* __restrict__ u_a, float* __restrict__ cc) {
  int b = blockIdx.x, tr = b >> 1, side = b & 1;
  int c = threadIdx.x;
  const float* d  = side ? wda_all + (tr + 1) * 512 : wsa_all + (tr + 1) * 1024;
  const float* lw = side ? ln_a_w + tr * HD : ln_v_w + tr * HD;
  const float* lb = side ? ln_a_b + tr * HD : ln_v_b + tr * HD;
  float dv = d[c];
  float uu = lw[c] * dv;
  float bv = lb[c] * dv;
  (side ? u_a : u_v)[tr * 512 + c] = uu;
  for (int off = 32; off; off >>= 1) { uu += __shfl_down(uu, off); bv += __shfl_down(bv, off); }
  __shared__ float s1[8], s2[8];
  int lane = c & 63, wid = c >> 6;
  if (lane == 0) { s1[wid] = uu; s2[wid] = bv; }
  __syncthreads();
  if (c == 0) {
    float a = 0, bb = 0;
    for (int i = 0; i < 8; ++i) { a += s1[i]; bb += s2[i]; }
    cc[tr * 4 + side * 2] = a;
    cc[tr * 4 + side * 2 + 1] = bb;
  }
}

__global__ __launch_bounds__(256) void initab_kernel(float* __restrict__ Av,
    float* __restrict__ Bv, float* __restrict__ Aa, float* __restrict__ Ba) {
  int i = blockIdx.x * 256 + threadIdx.x;
  if (i < NB) { Av[i] = 1.f; Bv[i] = 0.f; Aa[i] = 1.f; Ba[i] = 0.f; }
}

// ---- edge accumulation (shfl-batched CSR walk, bf16 messages) --------------
__device__ inline void acc_edges(const unsigned short* __restrict__ h,
    const int* __restrict__ rp, const int* __restrict__ eidx,
    const int* __restrict__ esrc, const float* __restrict__ ew,
    int d, int lane, float4& a0, float4& a1) {
  int beg = rp[d], end = rp[d + 1];
  for (int base = beg; base < end; base += 64) {
    int cnt = end - base; if (cnt > 64) cnt = 64;
    int s = 0; float w = 0.f;
    if (lane < cnt) {
      int e = eidx[base + lane];
      s = esrc[e];
      w = ew[e];
    }
    for (int j = 0; j < cnt; ++j) {
      int sj = __shfl(s, j);
      float wj = __shfl(w, j);
      ushort8 hv = *(const ushort8*)(h + (size_t)sj * HD + lane * 8);
      a0.x += wj * bf2f(hv[0]); a0.y += wj * bf2f(hv[1]);
      a0.z += wj * bf2f(hv[2]); a0.w += wj * bf2f(hv[3]);
      a1.x += wj * bf2f(hv[4]); a1.y += wj * bf2f(hv[5]);
      a1.z += wj * bf2f(hv[6]); a1.w += wj * bf2f(hv[7]);
    }
  }
}

// ---- merged gather: aa GCN + inline-softmax va GAT + vv GCN ----------------
// Writes bf16 relu'd features (Pb/Qb) for the next GEMM; fp32 Q on last layer
// for the readout. Block-local stats + fused next-layer logit dot.
__global__ __launch_bounds__(256) void gather_all(
    const unsigned short* __restrict__ S_a, const unsigned short* __restrict__ S_s,
    const unsigned short* __restrict__ S_v,
    const int* __restrict__ rp_aa, const int* __restrict__ ex_aa, const int* __restrict__ ei_aa,
    const float* __restrict__ ew_aa,
    const int* __restrict__ rp_va, const int* __restrict__ ex_va, const int* __restrict__ ei_va,
    const int* __restrict__ rp_vv, const int* __restrict__ ex_vv, const int* __restrict__ ei_vv,
    const float* __restrict__ ew_vv,
    const float* __restrict__ b_aa, const float* __restrict__ b_gat,
    const float* __restrict__ b_vv,
    const float* __restrict__ tv_cur, const float* __restrict__ ta_cur,
    const float* __restrict__ Av, const float* __restrict__ Bv,
    const float* __restrict__ Aa, const float* __restrict__ Ba,
    const float* __restrict__ u_v, const float* __restrict__ u_a,
    float* __restrict__ tv_next, float* __restrict__ ta_next,
    float* __restrict__ Q, unsigned short* __restrict__ Qb,
    unsigned short* __restrict__ Pb,
    float* __restrict__ psum, float* __restrict__ psq, int cdots, int wlast) {
  int blk = blockIdx.x;
  int wv = threadIdx.x >> 6;
  int idx = blk * 4 + wv;
  int lane = threadIdx.x & 63;
  float4 a0, a1;
  bool audio = idx < NA;
  if (audio) {
    a0 = *(const float4*)(b_aa + lane * 8);
    a1 = *(const float4*)(b_aa + lane * 8 + 4);
    float4 c0 = *(const float4*)(b_gat + lane * 8);
    float4 c1 = *(const float4*)(b_gat + lane * 8 + 4);
    a0.x += c0.x; a0.y += c0.y; a0.z += c0.z; a0.w += c0.w;
    a1.x += c1.x; a1.y += c1.y; a1.z += c1.z; a1.w += c1.w;
    acc_edges(S_a, rp_aa, ex_aa, ei_aa, ew_aa, idx, lane, a0, a1);
    int beg = rp_va[idx], end = rp_va[idx + 1];
    if (end > beg) {
      int gd = idx / 100;
      float ld = Aa[gd] * ta_cur[idx] + Ba[gd];
      float ssum = 0.f;
      for (int base = beg; base < end; base += 64) {
        int cnt = end - base; if (cnt > 64) cnt = 64;
        float ex = 0.f;
        if (lane < cnt) {
          int e = ex_va[base + lane];
          int s = ei_va[e];
          int gs = s / 40;
          float l = Av[gs] * tv_cur[s] + Bv[gs] + ld;
          l = (l > 0.f) ? l : 0.2f * l;
          ex = __expf(l);
        }
        float t = ex;
        for (int off = 32; off; off >>= 1) t += __shfl_down(t, off);
        ssum += __shfl(t, 0);
      }
      float inv = 1.f / ssum;
      for (int base = beg; base < end; base += 64) {
        int cnt = end - base; if (cnt > 64) cnt = 64;
        int s = 0; float ex = 0.f;
        if (lane < cnt) {
          int e = ex_va[base + lane];
          s = ei_va[e];
          int gs = s / 40;
          float l = Av[gs] * tv_cur[s] + Bv[gs] + ld;
          l = (l > 0.f) ? l : 0.2f * l;
          ex = __expf(l);
        }
        for (int j = 0; j < cnt; ++j) {
          int sj = __shfl(s, j);
          float wj = __shfl(ex, j) * inv;
          ushort8 hv = *(const ushort8*)(S_s + (size_t)sj * HD + lane * 8);
          a0.x += wj * bf2f(hv[0]); a0.y += wj * bf2f(hv[1]);
          a0.z += wj * bf2f(hv[2]); a0.w += wj * bf2f(hv[3]);
          a1.x += wj * bf2f(hv[4]); a1.y += wj * bf2f(hv[5]);
          a1.z += wj * bf2f(hv[6]); a1.w += wj * bf2f(hv[7]);
        }
      }
    }
  } else {
    int d = idx - NA;
    a0 = *(const float4*)(b_vv + lane * 8);
    a1 = *(const float4*)(b_vv + lane * 8 + 4);
    acc_edges(S_v, rp_vv, ex_vv, ei_vv, ew_vv, d, lane, a0, a1);
  }
  // relu values (shared by stats, t-dot, and the bf16 feature write)
  float4 r0, r1;
  r0.x = fmaxf(a0.x, 0.f); r0.y = fmaxf(a0.y, 0.f);
  r0.z = fmaxf(a0.z, 0.f); r0.w = fmaxf(a0.w, 0.f);
  r1.x = fmaxf(a1.x, 0.f); r1.y = fmaxf(a1.y, 0.f);
  r1.z = fmaxf(a1.z, 0.f); r1.w = fmaxf(a1.w, 0.f);
  // outputs
  if (audio) {
    if (wlast) {
      float* op = Q + (size_t)idx * HD + lane * 8;
      *(float4*)(op) = a0;
      *(float4*)(op + 4) = a1;
    } else {
      ushort8 ob;
      ob[0] = f2bf(r0.x); ob[1] = f2bf(r0.y); ob[2] = f2bf(r0.z); ob[3] = f2bf(r0.w);
      ob[4] = f2bf(r1.x); ob[5] = f2bf(r1.y); ob[6] = f2bf(r1.z); ob[7] = f2bf(r1.w);
      *(ushort8*)(Qb + (size_t)idx * HD + lane * 8) = ob;
    }
  } else {
    ushort8 ob;
    ob[0] = f2bf(r0.x); ob[1] = f2bf(r0.y); ob[2] = f2bf(r0.z); ob[3] = f2bf(r0.w);
    ob[4] = f2bf(r1.x); ob[5] = f2bf(r1.y); ob[6] = f2bf(r1.z); ob[7] = f2bf(r1.w);
    *(ushort8*)(Pb + (size_t)(idx - NA) * HD + lane * 8) = ob;
  }
  // stats partials (non-atomic per block)
  float rs2 = r0.x + r0.y + r0.z + r0.w + r1.x + r1.y + r1.z + r1.w;
  float rq2 = r0.x * r0.x + r0.y * r0.y + r0.z * r0.z + r0.w * r0.w
            + r1.x * r1.x + r1.y * r1.y + r1.z * r1.z + r1.w * r1.w;
  for (int off = 32; off; off >>= 1) {
    rs2 += __shfl_down(rs2, off);
    rq2 += __shfl_down(rq2, off);
  }
  __shared__ float bs[4], bq[4];
  if (lane == 0) { bs[wv] = rs2; bq[wv] = rq2; }
  if (cdots) {
    const float* u = audio ? u_a : u_v;
    float4 u0 = *(const float4*)(u + lane * 8);
    float4 u1 = *(const float4*)(u + lane * 8 + 4);
    float tn = u0.x * r0.x + u0.y * r0.y + u0.z * r0.z + u0.w * r0.w
             + u1.x * r1.x + u1.y * r1.y + u1.z * r1.z + u1.w * r1.w;
    for (int off = 32; off; off >>= 1) tn += __shfl_down(tn, off);
    if (lane == 0) {
      if (audio) ta_next[idx] = tn;
      else       tv_next[idx - NA] = tn;
    }
  }
  __syncthreads();
  if (threadIdx.x == 0) {
    psum[blk] = bs[0] + bs[1] + bs[2] + bs[3];
    psq[blk]  = bq[0] + bq[1] + bq[2] + bq[3];
  }
}

// ---- finalize: per-graph mean/rstd (+ next-layer logit affine A,B) ---------
__global__ __launch_bounds__(256) void finalize_kernel(const float* __restrict__ psum,
    const float* __restrict__ psq,
    float* __restrict__ mean_a, float* __restrict__ rstd_a,
    float* __restrict__ mean_v, float* __restrict__ rstd_v,
    float* __restrict__ Aa, float* __restrict__ Ba,
    float* __restrict__ Av, float* __restrict__ Bv,
    const float* __restrict__ cc, int tr, int wnext) {
  int i = blockIdx.x * 256 + threadIdx.x;
  if (i >= 2 * NB) return;
  bool aud = i < NB;
  int g = aud ? i : i - NB;
  int pbase = aud ? g * 25 : ABLK + g * 10;
  int pcnt = aud ? 25 : 10;
  float s = 0.f, q = 0.f;
  for (int k = 0; k < pcnt; ++k) { s += psum[pbase + k]; q += psq[pbase + k]; }
  float M = aud ? 100.f * 512.f : 40.f * 512.f;
  float mean = s / M;
  float var = q / M - mean * mean;
  float rstd = rsqrtf(fmaxf(var, 0.f) + 1e-5f);
  if (aud) { mean_a[g] = mean; rstd_a[g] = rstd; }
  else     { mean_v[g] = mean; rstd_v[g] = rstd; }
  if (wnext) {
    float c1 = cc[tr * 4 + (aud ? 2 : 0)];
    float c2 = cc[tr * 4 + (aud ? 2 : 0) + 1];
    float A = rstd, B = -rstd * mean * c1 + c2;
    if (aud) { Aa[g] = A; Ba[g] = B; }
    else     { Av[g] = A; Bv[g] = B; }
  }
}

// ------- readout with inline final-layer norm affine ------------------------
__global__ __launch_bounds__(512) void readout_kernel(const float* __restrict__ xa,
    const float* __restrict__ att_w,
    const float* __restrict__ mean_a, const float* __restrict__ rstd_a,
    const float* __restrict__ lw, const float* __restrict__ lb,
    float* __restrict__ ge) {
  int g = blockIdx.x;
  int tid = threadIdx.x;
  int lane = tid & 63, wid = tid >> 6;
  const float* xg = xa + (size_t)g * 100 * HD;
  float mean = mean_a[g], rstd = rstd_a[g];
  __shared__ float gv[112];
  for (int n = wid; n < 100; n += 8) {
    float p = 0.f;
#pragma unroll
    for (int j = 0; j < 8; ++j) {
      int c = j * 64 + lane;
      float o = lw[c] * (fmaxf(xg[(size_t)n * HD + c], 0.f) - mean) * rstd + lb[c];
      p += o * att_w[c];
    }
    for (int off = 32; off; off >>= 1) p += __shfl_down(p, off);
    if (lane == 0) gv[n] = p;
  }
  __syncthreads();
  __shared__ float inv_s;
  if (tid == 0) {
    float m = -1e30f;
    for (int n = 0; n < 100; ++n) m = fmaxf(m, gv[n]);
    float ssum = 0.f;
    for (int n = 0; n < 100; ++n) { float e = __expf(gv[n] - m); gv[n] = e; ssum += e; }
    inv_s = 1.0f / fmaxf(ssum, 1e-16f);
  }
  __syncthreads();
  float inv = inv_s;
  float wwc = lw[tid], bbc = lb[tid];
  float acc = 0.f;
  for (int n = 0; n < 100; ++n) {
    float o = wwc * (fmaxf(xg[(size_t)n * HD + tid], 0.f) - mean) * rstd + bbc;
    acc += gv[n] * o;
  }
  ge[(size_t)g * HD + tid] = acc * inv;
}

// ----------------------------------------------------------------------------
extern "C" void kernel_launch(void* const* d_in, const int* in_sizes, int n_in,
                              void* d_out, int out_size, void* d_ws, size_t ws_size,
                              hipStream_t stream) {
  const float* x_video = (const float*)d_in[0];
  const float* x_audio = (const float*)d_in[1];
  const float* ew_vv   = (const float*)d_in[2];
  const float* ew_aa   = (const float*)d_in[3];
  const float* W_vv0   = (const float*)d_in[4];
  const float* W_aa0   = (const float*)d_in[5];
  const float* W_src0  = (const float*)d_in[6];
  const float* W_dst0  = (const float*)d_in[7];
  const float* W_vv    = (const float*)d_in[8];
  const float* W_aa    = (const float*)d_in[9];
  const float* W_src   = (const float*)d_in[10];
  const float* W_dst   = (const float*)d_in[11];
  const float* b_vv    = (const float*)d_in[12];
  const float* b_aa    = (const float*)d_in[13];
  const float* b_gat   = (const float*)d_in[14];
  const float* a_src   = (const float*)d_in[15];
  const float* a_dst   = (const float*)d_in[16];
  const float* ln_v_w  = (const float*)d_in[17];
  const float* ln_v_b  = (const float*)d_in[18];
  const float* ln_a_w  = (const float*)d_in[19];
  const float* ln_a_b  = (const float*)d_in[20];
  const float* att_w   = (const float*)d_in[21];
  const float* lin_W   = (const float*)d_in[22];
  const float* lin_b   = (const float*)d_in[23];
  const int*   ei_vv   = (const int*)d_in[24];
  const int*   ei_aa   = (const int*)d_in[25];
  const int*   ei_va   = (const int*)d_in[26];

  // ---- workspace carve-up (4B units), ~228 MB ----
  const size_t WT_ELEMS = (size_t)HD * DV;
  const size_t REQ = (size_t)NA * HD + (size_t)NV * HD / 2
                   + (size_t)NA * HD / 2 + (size_t)NV * HD
                   + 2 * NV + 2 * NA + 4096 + 2048 + 3 * 512 * 2 + 16
                   + 8 * NB + 2 * GBLK + (size_t)NB * HD + 9 * 1024
                   + (NV + 1) + EVV + (NA + 1) + EAA + (NA + 1) + EVA
                   + 3 * (WT_ELEMS / 2) + 64;
  if (ws_size < REQ * sizeof(float)) return;

  float* p = (float*)d_ws;
  float* Q  = p; p += (size_t)NA * HD;            // fp32 (last layer); bf16 overlay earlier
  unsigned short* Qb = (unsigned short*)Q;        // bf16 relu'd audio features
  unsigned short* Pb = (unsigned short*)p; p += (size_t)NV * HD / 2;  // bf16 video feats
  unsigned short* S_a = (unsigned short*)p; p += (size_t)NA * HD / 2;
  unsigned short* S_s = (unsigned short*)p; p += (size_t)NV * HD / 2;
  unsigned short* S_v = (unsigned short*)p; p += (size_t)NV * HD / 2;
  float* tv0 = p; p += NV;
  float* tv1 = p; p += NV;
  float* ta0 = p; p += NA;
  float* ta1 = p; p += NA;
  float* wsa_all = p; p += 4096;
  float* wda_all = p; p += 2048;
  float* u_v = p; p += 3 * 512;
  float* u_a = p; p += 3 * 512;
  float* cc  = p; p += 16;
  float* mean_a = p; p += NB;
  float* rstd_a = p; p += NB;
  float* mean_v = p; p += NB;
  float* rstd_v = p; p += NB;
  float* Aa = p; p += NB;
  float* Ba = p; p += NB;
  float* Av = p; p += NB;
  float* Bv = p; p += NB;
  float* psum = p; p += GBLK;
  float* psq  = p; p += GBLK;
  float* ge   = p; p += (size_t)NB * HD;
  float* st_all = p; p += 9 * 1024;
  int* rp_vv = (int*)p; p += NV + 1;
  int* ex_vv = (int*)p; p += EVV;
  int* rp_aa = (int*)p; p += NA + 1;
  int* ex_aa = (int*)p; p += EAA;
  int* rp_va = (int*)p; p += NA + 1;
  int* ex_va = (int*)p; p += EVA;
  unsigned short* Wt_v = (unsigned short*)p; p += WT_ELEMS / 2;
  unsigned short* Wt_a = (unsigned short*)p; p += WT_ELEMS / 2;
  unsigned short* Wt_s = (unsigned short*)p; p += WT_ELEMS / 2;
  int* bsum = (int*)p; p += 64;

  int* degbuf = (int*)ta0;   // NA ints; dead before rowdots write ta0
  int* curbuf = (int*)ta1;

  // ---- build CSR (once) ----
  {
    struct { const int* dst; int* rp; int* ex; int N; int E; } g[3] = {
      { ei_vv + EVV, rp_vv, ex_vv, NV, EVV },
      { ei_aa + EAA, rp_aa, ex_aa, NA, EAA },
      { ei_va + EVA, rp_va, ex_va, NA, EVA },
    };
    for (int i = 0; i < 3; ++i) {
      int nb = (g[i].N + 1023) / 1024;
      hipMemsetAsync(degbuf, 0, (size_t)g[i].N * sizeof(int), stream);
      deg_kernel<<<(g[i].E + 255) / 256, 256, 0, stream>>>(g[i].dst, degbuf, g[i].E);
      scan1_kernel<<<nb, 256, 0, stream>>>(degbuf, bsum, g[i].N);
      scan2_kernel<<<1, 64, 0, stream>>>(bsum, nb, g[i].rp + g[i].N);
      scan3_kernel<<<nb, 256, 0, stream>>>(degbuf, bsum, g[i].rp, g[i].N);
      copy_kernel<<<(g[i].N + 255) / 256, 256, 0, stream>>>(g[i].rp, curbuf, g[i].N);
      fill_kernel<<<(g[i].E + 255) / 256, 256, 0, stream>>>(g[i].dst, curbuf, g[i].ex, g[i].E);
    }
  }

  // ---- prologue: logit-dot vectors, layer-0 dots, merged colsums ----
  for (int i = 0; i < NL; ++i) {
    const int Kv = (i == 0) ? DV : HD;
    const int Ka = (i == 0) ? DA : HD;
    const float* Ws = (i == 0) ? W_src0 : W_src + (size_t)(i - 1) * HD * HD;
    const float* Wd = (i == 0) ? W_dst0 : W_dst + (size_t)(i - 1) * HD * HD;
    rowdot_kernel<<<(Ka + 3) / 4, 256, 0, stream>>>(Wd, a_dst + i * HD, wda_all + i * 512, Ka, HD);
    rowdot_kernel<<<(Kv + 3) / 4, 256, 0, stream>>>(Ws, a_src + i * HD, wsa_all + i * 1024, Kv, HD);
  }
  rowdot_kernel<<<NA / 4, 256, 0, stream>>>(x_audio, wda_all, ta0, NA, DA);
  rowdot_kernel<<<NV / 4, 256, 0, stream>>>(x_video, wsa_all, tv0, NV, DV);
  uvec_kernel<<<6, 512, 0, stream>>>(wsa_all, wda_all, ln_v_w, ln_v_b, ln_a_w, ln_a_b,
                                     u_v, u_a, cc);
  initab_kernel<<<(NB + 255) / 256, 256, 0, stream>>>(Av, Bv, Aa, Ba);
  colsum9_kernel<<<dim3(8, 9), 512, 0, stream>>>(W_src, W_vv, W_aa,
      ln_v_w, ln_v_b, ln_a_w, ln_a_b, st_all);

  float* tv_cur = tv0; float* tv_nxt = tv1;
  float* ta_cur = ta0; float* ta_nxt = ta1;

  for (int i = 0; i < NL; ++i) {
    const int Kv = (i == 0) ? DV : HD;
    const int Ka = (i == 0) ? DA : HD;
    const float* Wv = (i == 0) ? W_vv0  : W_vv  + (size_t)(i - 1) * HD * HD;
    const float* Wa = (i == 0) ? W_aa0  : W_aa  + (size_t)(i - 1) * HD * HD;
    const float* Ws = (i == 0) ? W_src0 : W_src + (size_t)(i - 1) * HD * HD;
    const float* lnv_prev = (i == 0) ? nullptr : ln_v_w + (size_t)(i - 1) * HD;
    const float* lna_prev = (i == 0) ? nullptr : ln_a_w + (size_t)(i - 1) * HD;

    tcast_kernel<<<dim3(HD / 32, Kv / 32), 256, 0, stream>>>(Wv, lnv_prev, Wt_v, Kv);
    tcast_kernel<<<dim3(HD / 32, Ka / 32), 256, 0, stream>>>(Wa, lna_prev, Wt_a, Ka);
    tcast_kernel<<<dim3(HD / 32, Kv / 32), 256, 0, stream>>>(Ws, lnv_prev, Wt_s, Kv);

    if (i == 0)
      mfma_gemm3<0><<<GTOT, 256, 0, stream>>>(x_video, x_audio, Wt_s, Wt_v, Wt_a,
          S_s, S_v, S_a, Kv, Ka,
          nullptr, nullptr, nullptr, nullptr, nullptr, nullptr, nullptr);
    else {
      const float* stb = st_all + (size_t)(i - 1) * 3 * 1024;
      mfma_gemm3<1><<<GTOT, 256, 0, stream>>>(Pb, Qb, Wt_s, Wt_v, Wt_a,
          S_s, S_v, S_a, Kv, Ka,
          mean_v, rstd_v, mean_a, rstd_a,
          stb, stb + 1024, stb + 2048);
    }

    int cdots = (i + 1 < NL) ? 1 : 0;
    int wlast = (i == NL - 1) ? 1 : 0;
    gather_all<<<GBLK, 256, 0, stream>>>(S_a, S_s, S_v,
        rp_aa, ex_aa, ei_aa, ew_aa, rp_va, ex_va, ei_va,
        rp_vv, ex_vv, ei_vv, ew_vv,
        b_aa + i * HD, b_gat + i * HD, b_vv + i * HD,
        tv_cur, ta_cur, Av, Bv, Aa, Ba,
        u_v + i * 512, u_a + i * 512,
        tv_nxt, ta_nxt, Q, Qb, Pb, psum, psq, cdots, wlast);

    finalize_kernel<<<(2 * NB + 255) / 256, 256, 0, stream>>>(psum, psq,
        mean_a, rstd_a, mean_v, rstd_v, Aa, Ba, Av, Bv, cc, i, cdots);

    float* t;
    t = tv_cur; tv_cur = tv_nxt; tv_nxt = t;
    t = ta_cur; ta_cur = ta_nxt; ta_nxt = t;
  }

  // ---- readout (inline final norm affine) + final linear ----
  readout_kernel<<<NB, 512, 0, stream>>>(Q, att_w, mean_a, rstd_a,
      ln_a_w + (NL - 1) * HD, ln_a_b + (NL - 1) * HD, ge);
  gemm64<<<dim3(NOUT / 64, NB / 64), 256, 0, stream>>>(ge, lin_W, lin_b, (float*)d_out, NB, NOUT, HD);
}

// Round 16
// 1106.115 us; speedup vs baseline: 1.3750x; 1.0912x over previous
//
#include <hip/hip_runtime.h>

#define NB   512
#define NV   20480
#define NA   51200
#define EVV  163840
#define EAA  409600
#define EVA  61440
#define DV   1024
#define DA   128
#define HD   512
#define NOUT 128
#define NL   4

#define VTILES 160           // NV/128
#define ATILES 400           // NA/128
#define GSEC0  (VTILES * 4)  // 640  (hs)
#define GSEC1  (GSEC0 * 2)   // 1280 (hv)
#define GTOT   (GSEC1 + ATILES * 4)  // 2880
#define ABLK   (NA / 4)
#define GBLK   ((NA + NV) / 4)
#define ETOT   (EVV + EAA + EVA)     // 634880
#define WSLOT  ((size_t)HD * DV)     // wt_all slot stride (shorts)

typedef __attribute__((ext_vector_type(8))) short short8;
typedef __attribute__((ext_vector_type(8))) unsigned short ushort8;
typedef __attribute__((ext_vector_type(4))) float f32x4;

__device__ inline unsigned short f2bf(float f) {
  unsigned u = __float_as_uint(f);
  return (unsigned short)((u + 0x7fffu + ((u >> 16) & 1u)) >> 16);
}
__device__ inline float bf2f(unsigned short h) {
  return __uint_as_float((unsigned)h << 16);
}

// ---- merged MFMA GEMM; AFF=0: fp32 A (layer 0), AFF=1: bf16 A (pure copy) --
template <int AFF>
__global__ __launch_bounds__(256) void mfma_gemm3(const void* __restrict__ xvp,
    const void* __restrict__ xap,
    const unsigned short* __restrict__ Wt_s, const unsigned short* __restrict__ Wt_v,
    const unsigned short* __restrict__ Wt_a,
    unsigned short* __restrict__ S_s, unsigned short* __restrict__ S_v,
    unsigned short* __restrict__ S_a, int Kv, int Ka,
    const float* __restrict__ mean_v, const float* __restrict__ rstd_v,
    const float* __restrict__ mean_a, const float* __restrict__ rstd_a,
    const float* __restrict__ st_s, const float* __restrict__ st_v,
    const float* __restrict__ st_a) {
  __shared__ unsigned short As[128 * 40];
  __shared__ unsigned short Bs[128 * 40];
  const int id = blockIdx.x;
  const void* Ap; const unsigned short* Bt; unsigned short* C; int K; int lid;
  const float* stp; bool video;
  if (id < GSEC0)      { Ap = xvp; Bt = Wt_s; C = S_s; K = Kv; lid = id; stp = st_s; video = true; }
  else if (id < GSEC1) { Ap = xvp; Bt = Wt_v; C = S_v; K = Kv; lid = id - GSEC0; stp = st_v; video = true; }
  else                 { Ap = xap; Bt = Wt_a; C = S_a; K = Ka; lid = id - GSEC1; stp = st_a; video = false; }
  const int xcd = lid & 7;
  const int j = lid >> 3;
  const int bn = j & 3;
  const int bm = xcd + ((j >> 2) << 3);
  const int tid = threadIdx.x;
  const int l = tid & 63, wid = tid >> 6;
  const int wr = wid >> 1, wc = wid & 1;
  const int r = tid >> 1;
  const int kh = (tid & 1) << 4;

  const unsigned short* btp = Bt + (size_t)(bn * 128 + r) * K + kh;

  f32x4 acc[4][4] = {};
  const int fr = l & 15, fq = l >> 4;
  const int arow = (wr * 64 + fr) * 40 + fq * 8;
  const int brow = (wc * 64 + fr) * 40 + fq * 8;

  if (AFF == 0) {
    const float* ap = (const float*)Ap + (size_t)(bm * 128 + r) * K + kh;
    for (int k0 = 0; k0 < K; k0 += 32) {
      float4 f0 = *(const float4*)(ap + k0 + 0);
      float4 f1 = *(const float4*)(ap + k0 + 4);
      float4 f2 = *(const float4*)(ap + k0 + 8);
      float4 f3 = *(const float4*)(ap + k0 + 12);
      short8 bv0 = *(const short8*)(btp + k0);
      short8 bv1 = *(const short8*)(btp + k0 + 8);
      short8 p0, p1;
      p0[0] = (short)f2bf(f0.x); p0[1] = (short)f2bf(f0.y);
      p0[2] = (short)f2bf(f0.z); p0[3] = (short)f2bf(f0.w);
      p0[4] = (short)f2bf(f1.x); p0[5] = (short)f2bf(f1.y);
      p0[6] = (short)f2bf(f1.z); p0[7] = (short)f2bf(f1.w);
      p1[0] = (short)f2bf(f2.x); p1[1] = (short)f2bf(f2.y);
      p1[2] = (short)f2bf(f2.z); p1[3] = (short)f2bf(f2.w);
      p1[4] = (short)f2bf(f3.x); p1[5] = (short)f2bf(f3.y);
      p1[6] = (short)f2bf(f3.z); p1[7] = (short)f2bf(f3.w);
      __syncthreads();
      *(short8*)&As[r * 40 + kh] = p0;
      *(short8*)&As[r * 40 + kh + 8] = p1;
      *(short8*)&Bs[r * 40 + kh] = bv0;
      *(short8*)&Bs[r * 40 + kh + 8] = bv1;
      __syncthreads();
      short8 a[4], b[4];
#pragma unroll
      for (int m = 0; m < 4; ++m) a[m] = *(const short8*)&As[arow + m * 16 * 40];
#pragma unroll
      for (int n = 0; n < 4; ++n) b[n] = *(const short8*)&Bs[brow + n * 16 * 40];
#pragma unroll
      for (int m = 0; m < 4; ++m)
#pragma unroll
        for (int n = 0; n < 4; ++n)
          acc[m][n] = __builtin_amdgcn_mfma_f32_16x16x32_bf16(a[m], b[n], acc[m][n], 0, 0, 0);
    }
  } else {
    const unsigned short* ap = (const unsigned short*)Ap + (size_t)(bm * 128 + r) * K + kh;
    for (int k0 = 0; k0 < K; k0 += 32) {
      short8 av0 = *(const short8*)(ap + k0);
      short8 av1 = *(const short8*)(ap + k0 + 8);
      short8 bv0 = *(const short8*)(btp + k0);
      short8 bv1 = *(const short8*)(btp + k0 + 8);
      __syncthreads();
      *(short8*)&As[r * 40 + kh] = av0;
      *(short8*)&As[r * 40 + kh + 8] = av1;
      *(short8*)&Bs[r * 40 + kh] = bv0;
      *(short8*)&Bs[r * 40 + kh + 8] = bv1;
      __syncthreads();
      short8 a[4], b[4];
#pragma unroll
      for (int m = 0; m < 4; ++m) a[m] = *(const short8*)&As[arow + m * 16 * 40];
#pragma unroll
      for (int n = 0; n < 4; ++n) b[n] = *(const short8*)&Bs[brow + n * 16 * 40];
#pragma unroll
      for (int m = 0; m < 4; ++m)
#pragma unroll
        for (int n = 0; n < 4; ++n)
          acc[m][n] = __builtin_amdgcn_mfma_f32_16x16x32_bf16(a[m], b[n], acc[m][n], 0, 0, 0);
    }
  }

  // epilogue: per-row scalars (rstd, rstd*mean) + per-col (s, t)
#pragma unroll
  for (int m = 0; m < 4; ++m) {
    float rs4[4], rm4[4];
    if (AFF) {
#pragma unroll
      for (int j2 = 0; j2 < 4; ++j2) {
        int row = bm * 128 + wr * 64 + m * 16 + fq * 4 + j2;
        int g = video ? row / 40 : row / 100;
        float rs_ = video ? rstd_v[g] : rstd_a[g];
        float mn_ = video ? mean_v[g] : mean_a[g];
        rs4[j2] = rs_;
        rm4[j2] = rs_ * mn_;
      }
    }
#pragma unroll
    for (int n = 0; n < 4; ++n) {
      int col = bn * 128 + wc * 64 + n * 16 + fr;
      float s_c = 0.f, t_c = 0.f;
      if (AFF) { s_c = stp[col]; t_c = stp[512 + col]; }
#pragma unroll
      for (int j2 = 0; j2 < 4; ++j2) {
        int row = bm * 128 + wr * 64 + m * 16 + fq * 4 + j2;
        float val = acc[m][n][j2];
        if (AFF) val = rs4[j2] * val - rm4[j2] * s_c + t_c;
        C[(size_t)row * HD + col] = f2bf(val);
      }
    }
  }
}

// ------- all 12 weight transpose-casts in ONE launch ------------------------
// slot s: 0:Wv0(K=DV) 1:Wa0(K=DA) 2:Ws0(K=DV); 3+tr*3+{0,1,2}: Wv/Wa/Ws
__global__ __launch_bounds__(256) void tcast_all(const float* __restrict__ W_vv0,
    const float* __restrict__ W_aa0, const float* __restrict__ W_src0,
    const float* __restrict__ W_vv, const float* __restrict__ W_aa,
    const float* __restrict__ W_src,
    const float* __restrict__ ln_v_w, const float* __restrict__ ln_a_w,
    unsigned short* __restrict__ wt_all) {
  int s = blockIdx.z;
  const float* W; const float* ln = nullptr; int K;
  if (s == 0)      { W = W_vv0;  K = DV; }
  else if (s == 1) { W = W_aa0;  K = DA; }
  else if (s == 2) { W = W_src0; K = DV; }
  else {
    int tr = (s - 3) / 3, m = (s - 3) % 3;
    if (m == 0)      { W = W_vv  + (size_t)tr * HD * HD; ln = ln_v_w + tr * HD; }
    else if (m == 1) { W = W_aa  + (size_t)tr * HD * HD; ln = ln_a_w + tr * HD; }
    else             { W = W_src + (size_t)tr * HD * HD; ln = ln_v_w + tr * HD; }
    K = HD;
  }
  if ((int)blockIdx.y * 32 >= K) return;
  unsigned short* Wt = wt_all + (size_t)s * WSLOT;
  __shared__ float t[32][33];
  int n0 = blockIdx.x * 32, k0 = blockIdx.y * 32;
  int c = threadIdx.x & 31, rr = threadIdx.x >> 5;
#pragma unroll
  for (int i = 0; i < 4; ++i) {
    int row = rr + i * 8;
    t[row][c] = W[(size_t)(k0 + row) * HD + n0 + c];
  }
  __syncthreads();
  float lf = ln ? ln[k0 + c] : 1.0f;
#pragma unroll
  for (int i = 0; i < 4; ++i) {
    int row = rr + i * 8;
    Wt[(size_t)(n0 + row) * K + k0 + c] = f2bf(lf * t[c][row]);
  }
}

// ------- merged colsum for all 9 (layer-transition, matrix) pairs -----------
// m: 0=W_src (st_s), 1=W_vv (st_v), 2=W_aa (st_a)
__global__ __launch_bounds__(512) void colsum9_kernel(const float* __restrict__ W_src,
    const float* __restrict__ W_vv, const float* __restrict__ W_aa,
    const float* __restrict__ ln_v_w, const float* __restrict__ ln_v_b,
    const float* __restrict__ ln_a_w, const float* __restrict__ ln_a_b,
    float* __restrict__ st_all) {
  int tr = blockIdx.y / 3, m = blockIdx.y % 3;
  const float* W = (m == 0 ? W_src : m == 1 ? W_vv : W_aa) + (size_t)tr * HD * HD;
  const float* lnw = (m == 2 ? ln_a_w : ln_v_w) + tr * HD;
  const float* lnb = (m == 2 ? ln_a_b : ln_v_b) + tr * HD;
  float* st = st_all + (size_t)blockIdx.y * 1024;
  int c = threadIdx.x & 63, kq = threadIdx.x >> 6;
  int n = blockIdx.x * 64 + c;
  float s = 0.f, t = 0.f;
  for (int k = kq * 64; k < kq * 64 + 64; ++k) {
    float w = W[(size_t)k * HD + n];
    s += bf2f(f2bf(lnw[k] * w));
    t += lnb[k] * w;
  }
  __shared__ float sr[8][64], tr_[8][64];
  sr[kq][c] = s; tr_[kq][c] = t;
  __syncthreads();
  if (kq == 0) {
    for (int q = 1; q < 8; ++q) { s += sr[q][c]; t += tr_[q][c]; }
    st[n] = s; st[512 + n] = t;
  }
}

// ---------------- small fp32 GEMM (final linear only) -----------------------
__global__ __launch_bounds__(256) void gemm64(const float* __restrict__ A,
    const float* __restrict__ B, const float* __restrict__ bias,
    float* __restrict__ C, int M, int N, int K) {
  __shared__ float As[16][68];
  __shared__ float Bs[16][68];
  const int tid = threadIdx.x;
  const int bm = blockIdx.y, bn = blockIdx.x;
  const int tx = tid & 15, ty = tid >> 4;
  const int la_m = tid >> 2, la_k = (tid & 3) << 2;
  const int lb_k = tid >> 4, lb_n = (tid & 15) << 2;
  const float* Ab = A + (size_t)bm * 64 * K;
  const float* Bb = B + bn * 64;
  float acc[4][4] = {};
  for (int k0 = 0; k0 < K; k0 += 16) {
    float4 av = *(const float4*)(Ab + (size_t)la_m * K + k0 + la_k);
    float4 bv = *(const float4*)(Bb + (size_t)(k0 + lb_k) * N + lb_n);
    __syncthreads();
    As[la_k + 0][la_m] = av.x; As[la_k + 1][la_m] = av.y;
    As[la_k + 2][la_m] = av.z; As[la_k + 3][la_m] = av.w;
    *(float4*)&Bs[lb_k][lb_n] = bv;
    __syncthreads();
#pragma unroll
    for (int k = 0; k < 16; ++k) {
      float a0 = As[k][ty * 4 + 0], a1 = As[k][ty * 4 + 1];
      float a2 = As[k][ty * 4 + 2], a3 = As[k][ty * 4 + 3];
      float b0 = Bs[k][tx * 4 + 0], b1 = Bs[k][tx * 4 + 1];
      float b2 = Bs[k][tx * 4 + 2], b3 = Bs[k][tx * 4 + 3];
      acc[0][0] += a0 * b0; acc[0][1] += a0 * b1; acc[0][2] += a0 * b2; acc[0][3] += a0 * b3;
      acc[1][0] += a1 * b0; acc[1][1] += a1 * b1; acc[1][2] += a1 * b2; acc[1][3] += a1 * b3;
      acc[2][0] += a2 * b0; acc[2][1] += a2 * b1; acc[2][2] += a2 * b2; acc[2][3] += a2 * b3;
      acc[3][0] += a3 * b0; acc[3][1] += a3 * b1; acc[3][2] += a3 * b2; acc[3][3] += a3 * b3;
    }
  }
  const int col = bn * 64 + tx * 4;
  float4 bv = make_float4(0.f, 0.f, 0.f, 0.f);
  if (bias) bv = *(const float4*)(bias + col);
#pragma unroll
  for (int i = 0; i < 4; ++i) {
    size_t row = (size_t)bm * 64 + ty * 4 + i;
    float4 v = make_float4(acc[i][0] + bv.x, acc[i][1] + bv.y,
                           acc[i][2] + bv.z, acc[i][3] + bv.w);
    *(float4*)(C + row * N + col) = v;
  }
}

// ----------------------- merged CSR build -----------------------------------
__global__ __launch_bounds__(256) void deg_all(const int* __restrict__ dvv,
    const int* __restrict__ daa, const int* __restrict__ dva, int* __restrict__ D) {
  int e = blockIdx.x * 256 + threadIdx.x;
  if (e < EVV) { atomicAdd(D + dvv[e], 1); return; }
  e -= EVV;
  if (e < EAA) { atomicAdd(D + NV + daa[e], 1); return; }
  e -= EAA;
  if (e < EVA) atomicAdd(D + NV + NA + dva[e], 1);
}

__global__ __launch_bounds__(256) void scan1_all(const int* __restrict__ D,
    int* __restrict__ bsum) {
  __shared__ int sh[4];
  int b = blockIdx.x, tid = threadIdx.x;
  int off, lb;
  if (b < 20) { off = 0; lb = b; }
  else if (b < 70) { off = NV; lb = b - 20; }
  else { off = NV + NA; lb = b - 70; }
  int lane = tid & 63, wid = tid >> 6;
  int v = 0;
#pragma unroll
  for (int j = 0; j < 4; ++j) v += D[off + lb * 1024 + j * 256 + tid];
  for (int o = 32; o; o >>= 1) v += __shfl_down(v, o);
  if (lane == 0) sh[wid] = v;
  __syncthreads();
  if (tid == 0) bsum[b] = sh[0] + sh[1] + sh[2] + sh[3];
}

__global__ __launch_bounds__(256) void scan2_all(int* __restrict__ bsum,
    int* __restrict__ tot_vv, int* __restrict__ tot_aa, int* __restrict__ tot_va) {
  int w = threadIdx.x >> 6, lane = threadIdx.x & 63;
  if (w >= 3) return;
  int base = (w == 0) ? 0 : (w == 1) ? 20 : 70;
  int nb = (w == 0) ? 20 : 50;
  int v = (lane < nb) ? bsum[base + lane] : 0;
  int x = v;
#pragma unroll
  for (int o = 1; o < 64; o <<= 1) {
    int y = __shfl_up(x, o);
    if (lane >= o) x += y;
  }
  if (lane < nb) bsum[base + lane] = x - v;
  if (lane == 63) {
    if (w == 0) *tot_vv = x; else if (w == 1) *tot_aa = x; else *tot_va = x;
  }
}

__global__ __launch_bounds__(256) void scan3_all(const int* __restrict__ D,
    const int* __restrict__ bsum, int* __restrict__ rp_vv,
    int* __restrict__ rp_aa, int* __restrict__ rp_va) {
  __shared__ int wsum[4];
  int b = blockIdx.x, tid = threadIdx.x;
  int off, lb; int* rp;
  if (b < 20) { off = 0; lb = b; rp = rp_vv; }
  else if (b < 70) { off = NV; lb = b - 20; rp = rp_aa; }
  else { off = NV + NA; lb = b - 70; rp = rp_va; }
  int lane = tid & 63, wid = tid >> 6;
  int carry = bsum[b];
#pragma unroll
  for (int c = 0; c < 4; ++c) {
    int i = lb * 1024 + c * 256 + tid;
    int v = D[off + i];
    int x = v;
#pragma unroll
    for (int o = 1; o < 64; o <<= 1) {
      int y = __shfl_up(x, o);
      if (lane >= o) x += y;
    }
    if (lane == 63) wsum[wid] = x;
    __syncthreads();
    int woff = 0;
    for (int k = 0; k < wid; ++k) woff += wsum[k];
    rp[i] = carry + woff + x - v;
    carry += wsum[0] + wsum[1] + wsum[2] + wsum[3];
    __syncthreads();
  }
}

__global__ __launch_bounds__(256) void copy_all(const int* __restrict__ rp_vv,
    const int* __restrict__ rp_aa, const int* __restrict__ rp_va,
    int* __restrict__ C) {
  int i = blockIdx.x * 256 + threadIdx.x;
  if (i < NV) { C[i] = rp_vv[i]; return; }
  i -= NV;
  if (i < NA) { C[NV + i] = rp_aa[i]; return; }
  i -= NA;
  if (i < NA) C[NV + NA + i] = rp_va[i];
}

__global__ __launch_bounds__(256) void fill_all(const int* __restrict__ dvv,
    const int* __restrict__ daa, const int* __restrict__ dva,
    int* __restrict__ C, int* __restrict__ ex_vv, int* __restrict__ ex_aa,
    int* __restrict__ ex_va) {
  int e = blockIdx.x * 256 + threadIdx.x;
  if (e < EVV) { int pos = atomicAdd(C + dvv[e], 1); ex_vv[pos] = e; return; }
  e -= EVV;
  if (e < EAA) { int pos = atomicAdd(C + NV + daa[e], 1); ex_aa[pos] = e; return; }
  e -= EAA;
  if (e < EVA) { int pos = atomicAdd(C + NV + NA + dva[e], 1); ex_va[pos] = e; }
}

// ------- merged weight logit dots (8 sections, all K=HD) --------------------
__global__ __launch_bounds__(256) void wdot_kernel(const float* __restrict__ W_dst0,
    const float* __restrict__ W_dst, const float* __restrict__ W_src0,
    const float* __restrict__ W_src, const float* __restrict__ a_dst,
    const float* __restrict__ a_src, float* __restrict__ wda_all,
    float* __restrict__ wsa_all) {
  int r = blockIdx.x * 4 + (threadIdx.x >> 6);
  if (r >= 4224) return;
  int lane = threadIdx.x & 63;
  const float* W; const float* a; float* out; int lr;
  if (r < 128) { W = W_dst0; a = a_dst; out = wda_all; lr = r; }
  else if (r < 1664) {
    int t = (r - 128) / 512; lr = (r - 128) % 512;
    W = W_dst + (size_t)t * HD * HD; a = a_dst + (t + 1) * HD;
    out = wda_all + (t + 1) * 512;
  } else if (r < 2688) { W = W_src0; a = a_src; out = wsa_all; lr = r - 1664; }
  else {
    int t = (r - 2688) / 512; lr = (r - 2688) % 512;
    W = W_src + (size_t)t * HD * HD; a = a_src + (t + 1) * HD;
    out = wsa_all + (t + 1) * 1024;
  }
  const float* xp = W + (size_t)lr * HD;
  float p = 0.f;
  for (int k = lane; k < HD; k += 64) p += xp[k] * a[k];
  for (int o = 32; o; o >>= 1) p += __shfl_down(p, o);
  if (lane == 0) out[lr] = p;
}

// ------- merged layer-0 input logit dots ------------------------------------
__global__ __launch_bounds__(256) void xdot_kernel(const float* __restrict__ x_audio,
    const float* __restrict__ x_video, const float* __restrict__ wda0,
    const float* __restrict__ wsa0, float* __restrict__ ta0, float* __restrict__ tv0) {
  int r = blockIdx.x * 4 + (threadIdx.x >> 6);
  int lane = threadIdx.x & 63;
  if (r < NA) {
    const float* xp = x_audio + (size_t)r * DA;
    float p = 0.f;
    for (int k = lane; k < DA; k += 64) p += xp[k] * wda0[k];
    for (int o = 32; o; o >>= 1) p += __shfl_down(p, o);
    if (lane == 0) ta0[r] = p;
  } else if (r < NA + NV) {
    int lr = r - NA;
    const float* xp = x_video + (size_t)lr * DV;
    float p = 0.f;
    for (int k = lane; k < DV; k += 64) p += xp[k] * wsa0[k];
    for (int o = 32; o; o >>= 1) p += __shfl_down(p, o);
    if (lane == 0) tv0[lr] = p;
  }
}

// ---- u-vectors + scalars for logit-dot fusion ------------------------------
__global__ __launch_bounds__(512) void uvec_kernel(const float* __restrict__ wsa_all,
    const float* __restrict__ wda_all,
    const float* __restrict__ ln_v_w, const float* __restrict__ ln_v_b,
    const float* __restrict__ ln_a_w, const float* __restrict__ ln_a_b,
    float* __restrict__ u_v, float* __restrict__ u_a, float* __restrict__ cc) {
  int b = blockIdx.x, tr = b >> 1, side = b & 1;
  int c = threadIdx.x;
  const float* d  = side ? wda_all + (tr + 1) * 512 : wsa_all + (tr + 1) * 1024;
  const float* lw = side ? ln_a_w + tr * HD : ln_v_w + tr * HD;
  const float* lb = side ? ln_a_b + tr * HD : ln_v_b + tr * HD;
  float dv = d[c];
  float uu = lw[c] * dv;
  float bv = lb[c] * dv;
  (side ? u_a : u_v)[tr * 512 + c] = uu;
  for (int off = 32; off; off >>= 1) { uu += __shfl_down(uu, off); bv += __shfl_down(bv, off); }
  __shared__ float s1[8], s2[8];
  int lane = c & 63, wid = c >> 6;
  if (lane == 0) { s1[wid] = uu; s2[wid] = bv; }
  __syncthreads();
  if (c == 0) {
    float a = 0, bb = 0;
    for (int i = 0; i < 8; ++i) { a += s1[i]; bb += s2[i]; }
    cc[tr * 4 + side * 2] = a;
    cc[tr * 4 + side * 2 + 1] = bb;
  }
}

__global__ __launch_bounds__(256) void initab_kernel(float* __restrict__ Av,
    float* __restrict__ Bv, float* __restrict__ Aa, float* __restrict__ Ba) {
  int i = blockIdx.x * 256 + threadIdx.x;
  if (i < NB) { Av[i] = 1.f; Bv[i] = 0.f; Aa[i] = 1.f; Ba[i] = 0.f; }
}

// ---- edge accumulation (shfl-batched CSR walk, bf16 messages) --------------
__device__ inline void acc_edges(const unsigned short* __restrict__ h,
    const int* __restrict__ rp, const int* __restrict__ eidx,
    const int* __restrict__ esrc, const float* __restrict__ ew,
    int d, int lane, float4& a0, float4& a1) {
  int beg = rp[d], end = rp[d + 1];
  for (int base = beg; base < end; base += 64) {
    int cnt = end - base; if (cnt > 64) cnt = 64;
    int s = 0; float w = 0.f;
    if (lane < cnt) {
      int e = eidx[base + lane];
      s = esrc[e];
      w = ew[e];
    }
    for (int j = 0; j < cnt; ++j) {
      int sj = __shfl(s, j);
      float wj = __shfl(w, j);
      ushort8 hv = *(const ushort8*)(h + (size_t)sj * HD + lane * 8);
      a0.x += wj * bf2f(hv[0]); a0.y += wj * bf2f(hv[1]);
      a0.z += wj * bf2f(hv[2]); a0.w += wj * bf2f(hv[3]);
      a1.x += wj * bf2f(hv[4]); a1.y += wj * bf2f(hv[5]);
      a1.z += wj * bf2f(hv[6]); a1.w += wj * bf2f(hv[7]);
    }
  }
}

// ---- merged gather: aa GCN + inline-softmax va GAT + vv GCN ----------------
__global__ __launch_bounds__(256) void gather_all(
    const unsigned short* __restrict__ S_a, const unsigned short* __restrict__ S_s,
    const unsigned short* __restrict__ S_v,
    const int* __restrict__ rp_aa, const int* __restrict__ ex_aa, const int* __restrict__ ei_aa,
    const float* __restrict__ ew_aa,
    const int* __restrict__ rp_va, const int* __restrict__ ex_va, const int* __restrict__ ei_va,
    const int* __restrict__ rp_vv, const int* __restrict__ ex_vv, const int* __restrict__ ei_vv,
    const float* __restrict__ ew_vv,
    const float* __restrict__ b_aa, const float* __restrict__ b_gat,
    const float* __restrict__ b_vv,
    const float* __restrict__ tv_cur, const float* __restrict__ ta_cur,
    const float* __restrict__ Av, const float* __restrict__ Bv,
    const float* __restrict__ Aa, const float* __restrict__ Ba,
    const float* __restrict__ u_v, const float* __restrict__ u_a,
    float* __restrict__ tv_next, float* __restrict__ ta_next,
    float* __restrict__ Q, unsigned short* __restrict__ Qb,
    unsigned short* __restrict__ Pb,
    float* __restrict__ psum, float* __restrict__ psq, int cdots, int wlast) {
  int blk = blockIdx.x;
  int wv = threadIdx.x >> 6;
  int idx = blk * 4 + wv;
  int lane = threadIdx.x & 63;
  float4 a0, a1;
  bool audio = idx < NA;
  if (audio) {
    a0 = *(const float4*)(b_aa + lane * 8);
    a1 = *(const float4*)(b_aa + lane * 8 + 4);
    float4 c0 = *(const float4*)(b_gat + lane * 8);
    float4 c1 = *(const float4*)(b_gat + lane * 8 + 4);
    a0.x += c0.x; a0.y += c0.y; a0.z += c0.z; a0.w += c0.w;
    a1.x += c1.x; a1.y += c1.y; a1.z += c1.z; a1.w += c1.w;
    acc_edges(S_a, rp_aa, ex_aa, ei_aa, ew_aa, idx, lane, a0, a1);
    int beg = rp_va[idx], end = rp_va[idx + 1];
    if (end > beg) {
      int gd = idx / 100;
      float ld = Aa[gd] * ta_cur[idx] + Ba[gd];
      float ssum = 0.f;
      for (int base = beg; base < end; base += 64) {
        int cnt = end - base; if (cnt > 64) cnt = 64;
        float ex = 0.f;
        if (lane < cnt) {
          int e = ex_va[base + lane];
          int s = ei_va[e];
          int gs = s / 40;
          float l = Av[gs] * tv_cur[s] + Bv[gs] + ld;
          l = (l > 0.f) ? l : 0.2f * l;
          ex = __expf(l);
        }
        float t = ex;
        for (int off = 32; off; off >>= 1) t += __shfl_down(t, off);
        ssum += __shfl(t, 0);
      }
      float inv = 1.f / ssum;
      for (int base = beg; base < end; base += 64) {
        int cnt = end - base; if (cnt > 64) cnt = 64;
        int s = 0; float ex = 0.f;
        if (lane < cnt) {
          int e = ex_va[base + lane];
          s = ei_va[e];
          int gs = s / 40;
          float l = Av[gs] * tv_cur[s] + Bv[gs] + ld;
          l = (l > 0.f) ? l : 0.2f * l;
          ex = __expf(l);
        }
        for (int j = 0; j < cnt; ++j) {
          int sj = __shfl(s, j);
          float wj = __shfl(ex, j) * inv;
          ushort8 hv = *(const ushort8*)(S_s + (size_t)sj * HD + lane * 8);
          a0.x += wj * bf2f(hv[0]); a0.y += wj * bf2f(hv[1]);
          a0.z += wj * bf2f(hv[2]); a0.w += wj * bf2f(hv[3]);
          a1.x += wj * bf2f(hv[4]); a1.y += wj * bf2f(hv[5]);
          a1.z += wj * bf2f(hv[6]); a1.w += wj * bf2f(hv[7]);
        }
      }
    }
  } else {
    int d = idx - NA;
    a0 = *(const float4*)(b_vv + lane * 8);
    a1 = *(const float4*)(b_vv + lane * 8 + 4);
    acc_edges(S_v, rp_vv, ex_vv, ei_vv, ew_vv, d, lane, a0, a1);
  }
  float4 r0, r1;
  r0.x = fmaxf(a0.x, 0.f); r0.y = fmaxf(a0.y, 0.f);
  r0.z = fmaxf(a0.z, 0.f); r0.w = fmaxf(a0.w, 0.f);
  r1.x = fmaxf(a1.x, 0.f); r1.y = fmaxf(a1.y, 0.f);
  r1.z = fmaxf(a1.z, 0.f); r1.w = fmaxf(a1.w, 0.f);
  if (audio) {
    if (wlast) {
      float* op = Q + (size_t)idx * HD + lane * 8;
      *(float4*)(op) = a0;
      *(float4*)(op + 4) = a1;
    } else {
      ushort8 ob;
      ob[0] = f2bf(r0.x); ob[1] = f2bf(r0.y); ob[2] = f2bf(r0.z); ob[3] = f2bf(r0.w);
      ob[4] = f2bf(r1.x); ob[5] = f2bf(r1.y); ob[6] = f2bf(r1.z); ob[7] = f2bf(r1.w);
      *(ushort8*)(Qb + (size_t)idx * HD + lane * 8) = ob;
    }
  } else {
    ushort8 ob;
    ob[0] = f2bf(r0.x); ob[1] = f2bf(r0.y); ob[2] = f2bf(r0.z); ob[3] = f2bf(r0.w);
    ob[4] = f2bf(r1.x); ob[5] = f2bf(r1.y); ob[6] = f2bf(r1.z); ob[7] = f2bf(r1.w);
    *(ushort8*)(Pb + (size_t)(idx - NA) * HD + lane * 8) = ob;
  }
  float rs2 = r0.x + r0.y + r0.z + r0.w + r1.x + r1.y + r1.z + r1.w;
  float rq2 = r0.x * r0.x + r0.y * r0.y + r0.z * r0.z + r0.w * r0.w
            + r1.x * r1.x + r1.y * r1.y + r1.z * r1.z + r1.w * r1.w;
  for (int off = 32; off; off >>= 1) {
    rs2 += __shfl_down(rs2, off);
    rq2 += __shfl_down(rq2, off);
  }
  __shared__ float bs[4], bq[4];
  if (lane == 0) { bs[wv] = rs2; bq[wv] = rq2; }
  if (cdots) {
    const float* u = audio ? u_a : u_v;
    float4 u0 = *(const float4*)(u + lane * 8);
    float4 u1 = *(const float4*)(u + lane * 8 + 4);
    float tn = u0.x * r0.x + u0.y * r0.y + u0.z * r0.z + u0.w * r0.w
             + u1.x * r1.x + u1.y * r1.y + u1.z * r1.z + u1.w * r1.w;
    for (int off = 32; off; off >>= 1) tn += __shfl_down(tn, off);
    if (lane == 0) {
      if (audio) ta_next[idx] = tn;
      else       tv_next[idx - NA] = tn;
    }
  }
  __syncthreads();
  if (threadIdx.x == 0) {
    psum[blk] = bs[0] + bs[1] + bs[2] + bs[3];
    psq[blk]  = bq[0] + bq[1] + bq[2] + bq[3];
  }
}

// ---- finalize: per-graph mean/rstd (+ next-layer logit affine A,B) ---------
__global__ __launch_bounds__(256) void finalize_kernel(const float* __restrict__ psum,
    const float* __restrict__ psq,
    float* __restrict__ mean_a, float* __restrict__ rstd_a,
    float* __restrict__ mean_v, float* __restrict__ rstd_v,
    float* __restrict__ Aa, float* __restrict__ Ba,
    float* __restrict__ Av, float* __restrict__ Bv,
    const float* __restrict__ cc, int tr, int wnext) {
  int i = blockIdx.x * 256 + threadIdx.x;
  if (i >= 2 * NB) return;
  bool aud = i < NB;
  int g = aud ? i : i - NB;
  int pbase = aud ? g * 25 : ABLK + g * 10;
  int pcnt = aud ? 25 : 10;
  float s = 0.f, q = 0.f;
  for (int k = 0; k < pcnt; ++k) { s += psum[pbase + k]; q += psq[pbase + k]; }
  float M = aud ? 100.f * 512.f : 40.f * 512.f;
  float mean = s / M;
  float var = q / M - mean * mean;
  float rstd = rsqrtf(fmaxf(var, 0.f) + 1e-5f);
  if (aud) { mean_a[g] = mean; rstd_a[g] = rstd; }
  else     { mean_v[g] = mean; rstd_v[g] = rstd; }
  if (wnext) {
    float c1 = cc[tr * 4 + (aud ? 2 : 0)];
    float c2 = cc[tr * 4 + (aud ? 2 : 0) + 1];
    float A = rstd, B = -rstd * mean * c1 + c2;
    if (aud) { Aa[g] = A; Ba[g] = B; }
    else     { Av[g] = A; Bv[g] = B; }
  }
}

// ------- readout with inline final-layer norm affine ------------------------
__global__ __launch_bounds__(512) void readout_kernel(const float* __restrict__ xa,
    const float* __restrict__ att_w,
    const float* __restrict__ mean_a, const float* __restrict__ rstd_a,
    const float* __restrict__ lw, const float* __restrict__ lb,
    float* __restrict__ ge) {
  int g = blockIdx.x;
  int tid = threadIdx.x;
  int lane = tid & 63, wid = tid >> 6;
  const float* xg = xa + (size_t)g * 100 * HD;
  float mean = mean_a[g], rstd = rstd_a[g];
  __shared__ float gv[112];
  for (int n = wid; n < 100; n += 8) {
    float p = 0.f;
#pragma unroll
    for (int j = 0; j < 8; ++j) {
      int c = j * 64 + lane;
      float o = lw[c] * (fmaxf(xg[(size_t)n * HD + c], 0.f) - mean) * rstd + lb[c];
      p += o * att_w[c];
    }
    for (int off = 32; off; off >>= 1) p += __shfl_down(p, off);
    if (lane == 0) gv[n] = p;
  }
  __syncthreads();
  __shared__ float inv_s;
  if (tid == 0) {
    float m = -1e30f;
    for (int n = 0; n < 100; ++n) m = fmaxf(m, gv[n]);
    float ssum = 0.f;
    for (int n = 0; n < 100; ++n) { float e = __expf(gv[n] - m); gv[n] = e; ssum += e; }
    inv_s = 1.0f / fmaxf(ssum, 1e-16f);
  }
  __syncthreads();
  float inv = inv_s;
  float wwc = lw[tid], bbc = lb[tid];
  float acc = 0.f;
  for (int n = 0; n < 100; ++n) {
    float o = wwc * (fmaxf(xg[(size_t)n * HD + tid], 0.f) - mean) * rstd + bbc;
    acc += gv[n] * o;
  }
  ge[(size_t)g * HD + tid] = acc * inv;
}

// ----------------------------------------------------------------------------
extern "C" void kernel_launch(void* const* d_in, const int* in_sizes, int n_in,
                              void* d_out, int out_size, void* d_ws, size_t ws_size,
                              hipStream_t stream) {
  const float* x_video = (const float*)d_in[0];
  const float* x_audio = (const float*)d_in[1];
  const float* ew_vv   = (const float*)d_in[2];
  const float* ew_aa   = (const float*)d_in[3];
  const float* W_vv0   = (const float*)d_in[4];
  const float* W_aa0   = (const float*)d_in[5];
  const float* W_src0  = (const float*)d_in[6];
  const float* W_dst0  = (const float*)d_in[7];
  const float* W_vv    = (const float*)d_in[8];
  const float* W_aa    = (const float*)d_in[9];
  const float* W_src   = (const float*)d_in[10];
  const float* W_dst   = (const float*)d_in[11];
  const float* b_vv    = (const float*)d_in[12];
  const float* b_aa    = (const float*)d_in[13];
  const float* b_gat   = (const float*)d_in[14];
  const float* a_src   = (const float*)d_in[15];
  const float* a_dst   = (const float*)d_in[16];
  const float* ln_v_w  = (const float*)d_in[17];
  const float* ln_v_b  = (const float*)d_in[18];
  const float* ln_a_w  = (const float*)d_in[19];
  const float* ln_a_b  = (const float*)d_in[20];
  const float* att_w   = (const float*)d_in[21];
  const float* lin_W   = (const float*)d_in[22];
  const float* lin_b   = (const float*)d_in[23];
  const int*   ei_vv   = (const int*)d_in[24];
  const int*   ei_aa   = (const int*)d_in[25];
  const int*   ei_va   = (const int*)d_in[26];

  // ---- workspace carve-up (4B units), ~237 MB ----
  const size_t REQ = (size_t)NA * HD + (size_t)NV * HD / 2
                   + (size_t)NA * HD / 2 + (size_t)NV * HD
                   + 2 * NV + 2 * NA + 4096 + 2048 + 3 * 512 * 2 + 16
                   + 8 * NB + 2 * GBLK + (size_t)NB * HD + 9 * 1024
                   + (NV + 1) + EVV + (NA + 1) + EAA + (NA + 1) + EVA
                   + 12 * (WSLOT / 2) + 128;
  if (ws_size < REQ * sizeof(float)) return;

  float* p = (float*)d_ws;
  float* Q  = p; p += (size_t)NA * HD;            // fp32 (last layer); bf16 overlay earlier
  unsigned short* Qb = (unsigned short*)Q;
  unsigned short* Pb = (unsigned short*)p; p += (size_t)NV * HD / 2;
  unsigned short* S_a = (unsigned short*)p; p += (size_t)NA * HD / 2;
  unsigned short* S_s = (unsigned short*)p; p += (size_t)NV * HD / 2;
  unsigned short* S_v = (unsigned short*)p; p += (size_t)NV * HD / 2;
  float* tv0 = p; p += NV;
  float* tv1 = p; p += NV;
  float* ta0 = p; p += NA;
  float* ta1 = p; p += NA;
  float* wsa_all = p; p += 4096;
  float* wda_all = p; p += 2048;
  float* u_v = p; p += 3 * 512;
  float* u_a = p; p += 3 * 512;
  float* cc  = p; p += 16;
  float* mean_a = p; p += NB;
  float* rstd_a = p; p += NB;
  float* mean_v = p; p += NB;
  float* rstd_v = p; p += NB;
  float* Aa = p; p += NB;
  float* Ba = p; p += NB;
  float* Av = p; p += NB;
  float* Bv = p; p += NB;
  float* psum = p; p += GBLK;
  float* psq  = p; p += GBLK;
  float* ge   = p; p += (size_t)NB * HD;
  float* st_all = p; p += 9 * 1024;
  int* rp_vv = (int*)p; p += NV + 1;
  int* ex_vv = (int*)p; p += EVV;
  int* rp_aa = (int*)p; p += NA + 1;
  int* ex_aa = (int*)p; p += EAA;
  int* rp_va = (int*)p; p += NA + 1;
  int* ex_va = (int*)p; p += EVA;
  unsigned short* wt_all = (unsigned short*)p; p += 12 * (WSLOT / 2);
  int* bsum = (int*)p; p += 128;

  // CSR scratch overlays S_a (dead until layer-0 GEMM)
  int* D = (int*)S_a;
  int* C = D + (NV + 2 * NA);
  const int* dvv = ei_vv + EVV;
  const int* daa = ei_aa + EAA;
  const int* dva = ei_va + EVA;

  // ---- CSR build: 1 memset + 5 merged kernels ----
  hipMemsetAsync(D, 0, (size_t)(NV + 2 * NA) * sizeof(int), stream);
  deg_all<<<(ETOT + 255) / 256, 256, 0, stream>>>(dvv, daa, dva, D);
  scan1_all<<<120, 256, 0, stream>>>(D, bsum);
  scan2_all<<<1, 256, 0, stream>>>(bsum, rp_vv + NV, rp_aa + NA, rp_va + NA);
  scan3_all<<<120, 256, 0, stream>>>(D, bsum, rp_vv, rp_aa, rp_va);
  copy_all<<<(NV + 2 * NA + 255) / 256, 256, 0, stream>>>(rp_vv, rp_aa, rp_va, C);
  fill_all<<<(ETOT + 255) / 256, 256, 0, stream>>>(dvv, daa, dva, C, ex_vv, ex_aa, ex_va);

  // ---- prologue: merged logit dots, uvec, colsums, ALL weight tcasts ----
  wdot_kernel<<<4224 / 4, 256, 0, stream>>>(W_dst0, W_dst, W_src0, W_src,
                                            a_dst, a_src, wda_all, wsa_all);
  xdot_kernel<<<(NA + NV) / 4, 256, 0, stream>>>(x_audio, x_video, wda_all, wsa_all,
                                                 ta0, tv0);
  uvec_kernel<<<6, 512, 0, stream>>>(wsa_all, wda_all, ln_v_w, ln_v_b, ln_a_w, ln_a_b,
                                     u_v, u_a, cc);
  initab_kernel<<<(NB + 255) / 256, 256, 0, stream>>>(Av, Bv, Aa, Ba);
  colsum9_kernel<<<dim3(8, 9), 512, 0, stream>>>(W_src, W_vv, W_aa,
      ln_v_w, ln_v_b, ln_a_w, ln_a_b, st_all);
  tcast_all<<<dim3(HD / 32, DV / 32, 12), 256, 0, stream>>>(W_vv0, W_aa0, W_src0,
      W_vv, W_aa, W_src, ln_v_w, ln_a_w, wt_all);

  float* tv_cur = tv0; float* tv_nxt = tv1;
  float* ta_cur = ta0; float* ta_nxt = ta1;

  for (int i = 0; i < NL; ++i) {
    const int Kv = (i == 0) ? DV : HD;
    const int Ka = (i == 0) ? DA : HD;
    const unsigned short *Wt_v_i, *Wt_a_i, *Wt_s_i;
    if (i == 0) {
      Wt_v_i = wt_all + 0 * WSLOT; Wt_a_i = wt_all + 1 * WSLOT; Wt_s_i = wt_all + 2 * WSLOT;
    } else {
      int tr = i - 1;
      Wt_v_i = wt_all + (size_t)(3 + tr * 3 + 0) * WSLOT;
      Wt_a_i = wt_all + (size_t)(3 + tr * 3 + 1) * WSLOT;
      Wt_s_i = wt_all + (size_t)(3 + tr * 3 + 2) * WSLOT;
    }

    if (i == 0)
      mfma_gemm3<0><<<GTOT, 256, 0, stream>>>(x_video, x_audio, Wt_s_i, Wt_v_i, Wt_a_i,
          S_s, S_v, S_a, Kv, Ka,
          nullptr, nullptr, nullptr, nullptr, nullptr, nullptr, nullptr);
    else {
      // colsum9 slot order: m0=W_src -> st_s, m1=W_vv -> st_v, m2=W_aa -> st_a
      const float* stb = st_all + (size_t)(i - 1) * 3 * 1024;
      mfma_gemm3<1><<<GTOT, 256, 0, stream>>>(Pb, Qb, Wt_s_i, Wt_v_i, Wt_a_i,
          S_s, S_v, S_a, Kv, Ka,
          mean_v, rstd_v, mean_a, rstd_a,
          stb, stb + 1024, stb + 2048);
    }

    int cdots = (i + 1 < NL) ? 1 : 0;
    int wlast = (i == NL - 1) ? 1 : 0;
    gather_all<<<GBLK, 256, 0, stream>>>(S_a, S_s, S_v,
        rp_aa, ex_aa, ei_aa, ew_aa, rp_va, ex_va, ei_va,
        rp_vv, ex_vv, ei_vv, ew_vv,
        b_aa + i * HD, b_gat + i * HD, b_vv + i * HD,
        tv_cur, ta_cur, Av, Bv, Aa, Ba,
        u_v + i * 512, u_a + i * 512,
        tv_nxt, ta_nxt, Q, Qb, Pb, psum, psq, cdots, wlast);

    finalize_kernel<<<(2 * NB + 255) / 256, 256, 0, stream>>>(psum, psq,
        mean_a, rstd_a, mean_v, rstd_v, Aa, Ba, Av, Bv, cc, i, cdots);

    float* t;
    t = tv_cur; tv_cur = tv_nxt; tv_nxt = t;
    t = ta_cur; ta_cur = ta_nxt; ta_nxt = t;
  }

  // ---- readout (inline final norm affine) + final linear ----
  readout_kernel<<<NB, 512, 0, stream>>>(Q, att_w, mean_a, rstd_a,
      ln_a_w + (NL - 1) * HD, ln_a_b + (NL - 1) * HD, ge);
  gemm64<<<dim3(NOUT / 64, NB / 64), 256, 0, stream>>>(ge, lin_W, lin_b, (float*)d_out, NB, NOUT, HD);
}